// Round 6
// baseline (1708.020 us; speedup 1.0000x reference)
//
#include <hip/hip_runtime.h>

#define LSEQ 4096
#define NH   16
#define DH   64
#define WIN  256
#define DM   1024

// Plain fp32 NT GEMM, correct by construction:
// C[m][n] = sum_k A[m][k] * B[n][k],  A: 4096 x 1024, B: 1024 x 1024.
// grid (128, 32); 256 threads; 32x32 LDS tiles (+1 pad); 2x2 outputs/thread.
__global__ __launch_bounds__(256) void gemm_nt(
    const float* __restrict__ A, const float* __restrict__ B,
    float* __restrict__ C)
{
  __shared__ float As[32][33];
  __shared__ float Bs[32][33];
  const int m0 = blockIdx.x * 32;
  const int n0 = blockIdx.y * 32;
  const int tx = threadIdx.x & 15;
  const int ty = threadIdx.x >> 4;

  float acc[2][2] = {{0.f, 0.f}, {0.f, 0.f}};

  for (int kt = 0; kt < DM; kt += 32) {
    #pragma unroll
    for (int p = 0; p < 4; ++p) {
      const int e = threadIdx.x + 256 * p;
      const int r = e >> 5, c = e & 31;
      As[r][c] = A[(size_t)(m0 + r) * DM + kt + c];
      Bs[r][c] = B[(size_t)(n0 + r) * DM + kt + c];
    }
    __syncthreads();
    #pragma unroll 8
    for (int kk = 0; kk < 32; ++kk) {
      const float a0 = As[ty][kk],      a1 = As[ty + 16][kk];
      const float b0 = Bs[tx][kk],      b1 = Bs[tx + 16][kk];
      acc[0][0] += a0 * b0;  acc[0][1] += a0 * b1;
      acc[1][0] += a1 * b0;  acc[1][1] += a1 * b1;
    }
    __syncthreads();
  }

  #pragma unroll
  for (int i = 0; i < 2; ++i)
    #pragma unroll
    for (int j = 0; j < 2; ++j)
      C[(size_t)(m0 + ty + 16 * i) * DM + (n0 + tx + 16 * j)] = acc[i][j];
}

// Scalar sliding-window attention, one 64-lane wave per (query, head).
// Q,K,V plain fp32 [L][DM] (col = h*64 + d).
__global__ __launch_bounds__(64) void attn_f32(
    const float* __restrict__ Q, const float* __restrict__ K,
    const float* __restrict__ V, float* __restrict__ O)
{
  const int q    = blockIdx.x;
  const int h    = blockIdx.y;
  const int lane = threadIdx.x;
  const int j0   = (q >= WIN - 1) ? (q - WIN + 1) : 0;
  const int nk   = q - j0 + 1;              // 1..256 valid keys
  __shared__ float ps[256];

  const float* qrow = Q + (size_t)q * DM + h * DH;

  // phase 1: lane l scores keys j0 + l + 64*m
  float sc[4];
  float lm = -1e30f;
  #pragma unroll
  for (int m = 0; m < 4; ++m) {
    const int j = j0 + lane + 64 * m;
    float a = -1e30f;
    if (j <= q) {
      const float* krow = K + (size_t)j * DM + h * DH;
      float acc = 0.f;
      for (int d = 0; d < DH; ++d) acc += qrow[d] * krow[d];
      a = acc * 0.125f;                     // 1/sqrt(64)
    }
    sc[m] = a;
    lm = fmaxf(lm, a);
  }
  #pragma unroll
  for (int o = 1; o < 64; o <<= 1) lm = fmaxf(lm, __shfl_xor(lm, o));

  float ls = 0.f;
  #pragma unroll
  for (int m = 0; m < 4; ++m) { sc[m] = __expf(sc[m] - lm); ls += sc[m]; }
  #pragma unroll
  for (int o = 1; o < 64; o <<= 1) ls += __shfl_xor(ls, o);

  #pragma unroll
  for (int m = 0; m < 4; ++m) ps[lane + 64 * m] = sc[m];
  __syncthreads();

  // phase 2: lane = output dim d; V reads are lane-coalesced per key
  float o = 0.f;
  for (int t = 0; t < nk; ++t)
    o += ps[t] * V[(size_t)(j0 + t) * DM + h * DH + lane];
  O[(size_t)q * DM + h * DH + lane] = o / ls;
}

extern "C" void kernel_launch(void* const* d_in, const int* in_sizes, int n_in,
                              void* d_out, int out_size, void* d_ws, size_t ws_size,
                              hipStream_t stream) {
  const float* x  = (const float*)d_in[0];
  const float* Wq = (const float*)d_in[1];
  const float* Wk = (const float*)d_in[2];
  const float* Wv = (const float*)d_in[3];
  const float* Wo = (const float*)d_in[4];
  float* out = (float*)d_out;               // reference output dtype: float32

  const size_t nElem = (size_t)LSEQ * DM;   // 4M floats per activation buffer
  float* Qf = (float*)d_ws;                 // 16 MiB
  float* Kf = Qf + nElem;                   // 16 MiB
  float* Vf = Kf + nElem;                   // 16 MiB
  float* Af = Vf + nElem;                   // 16 MiB (ws >= 64 MiB, proven R4)

  gemm_nt<<<dim3(128, 32), 256, 0, stream>>>(x, Wq, Qf);
  gemm_nt<<<dim3(128, 32), 256, 0, stream>>>(x, Wk, Kf);
  gemm_nt<<<dim3(128, 32), 256, 0, stream>>>(x, Wv, Vf);
  attn_f32<<<dim3(LSEQ, NH), 64, 0, stream>>>(Qf, Kf, Vf, Af);
  gemm_nt<<<dim3(128, 32), 256, 0, stream>>>(Af, Wo, out);
}

// Round 7
// 203.852 us; speedup vs baseline: 8.3787x; 8.3787x over previous
//
#include <hip/hip_runtime.h>

using bf16x8 = __attribute__((ext_vector_type(8))) short;
using u16x8  = __attribute__((ext_vector_type(8))) unsigned short;
using f32x4  = __attribute__((ext_vector_type(4))) float;

#define LSEQ   4096
#define NH     16
#define DH     64
#define WIN    256
#define DM     1024

// async global->LDS, 16B per lane; LDS dest is wave-uniform base + lane*16
__device__ __forceinline__ void gl2lds16(const void* g, void* l) {
  __builtin_amdgcn_global_load_lds(
      (const __attribute__((address_space(1))) unsigned int*)g,
      (__attribute__((address_space(3))) unsigned int*)l,
      16, 0, 0);
}

// fp32 -> bf16 RNE (finite inputs only)
__device__ __forceinline__ unsigned short f2bf(float f) {
  unsigned int u = __float_as_uint(f);
  u += 0x7fffu + ((u >> 16) & 1u);
  return (unsigned short)(u >> 16);
}

// ---- fp32 -> bf16 conversion of x and the 4 weight matrices --------------
// grid (2048, 5): seg 0 = x (4M elems), segs 1..4 = W (1M elems each)
__global__ __launch_bounds__(256) void cvt5(
    const float* __restrict__ p0, const float* __restrict__ p1,
    const float* __restrict__ p2, const float* __restrict__ p3,
    const float* __restrict__ p4,
    unsigned short* __restrict__ q0, unsigned short* __restrict__ q1,
    unsigned short* __restrict__ q2, unsigned short* __restrict__ q3,
    unsigned short* __restrict__ q4)
{
  const int seg = blockIdx.y;
  const float* src = (seg == 0) ? p0 : (seg == 1) ? p1 : (seg == 2) ? p2
                     : (seg == 3) ? p3 : p4;
  unsigned short* dst = (seg == 0) ? q0 : (seg == 1) ? q1 : (seg == 2) ? q2
                        : (seg == 3) ? q3 : q4;
  const int n = (seg == 0) ? (LSEQ * DM) : (DM * DM);
  const int i = (blockIdx.x * 256 + threadIdx.x) * 8;
  if (i >= n) return;
  const f32x4 f0 = *(const f32x4*)(src + i);
  const f32x4 f1 = *(const f32x4*)(src + i + 4);
  u16x8 o;
  o[0] = f2bf(f0[0]); o[1] = f2bf(f0[1]); o[2] = f2bf(f0[2]); o[3] = f2bf(f0[3]);
  o[4] = f2bf(f1[0]); o[5] = f2bf(f1[1]); o[6] = f2bf(f1[2]); o[7] = f2bf(f1[3]);
  *(u16x8*)(dst + i) = o;
}

// C = X[m0:m0+128, :] * W[n0:n0+128, :]^T   (NT GEMM, K=DM=1024, bf16 in, fp32 acc)
// Validated (R2==R4 bit-match): global_load_lds staging + 16x16x32 MFMA.
__device__ __forceinline__ void gemm_tile(
    const unsigned short* __restrict__ X,
    const unsigned short* __restrict__ W,
    int m0, int n0,
    unsigned short* As, unsigned short* Bs,
    f32x4 (&acc)[4][4])
{
  const int tid  = threadIdx.x;
  const int lane = tid & 63;
  const int wave = tid >> 6;
  const int wm = wave >> 1, wn = wave & 1;
  const int fr = lane & 15, quad = lane >> 4;

  const f32x4 zero = {0.f, 0.f, 0.f, 0.f};
  #pragma unroll
  for (int i = 0; i < 4; ++i)
    #pragma unroll
    for (int j = 0; j < 4; ++j)
      acc[i][j] = zero;

  // staging map: chunk c (0..511) -> LDS byte c*16 == row(c>>2)*64B + (c&3)*16B
  const int c0 = tid, c1 = tid + 256;
  const unsigned short* xa0 = X + (size_t)(m0 + (c0 >> 2)) * DM + (c0 & 3) * 8;
  const unsigned short* xa1 = X + (size_t)(m0 + (c1 >> 2)) * DM + (c1 & 3) * 8;
  const unsigned short* wb0 = W + (size_t)(n0 + (c0 >> 2)) * DM + (c0 & 3) * 8;
  const unsigned short* wb1 = W + (size_t)(n0 + (c1 >> 2)) * DM + (c1 & 3) * 8;
  char* la0 = (char*)As + c0 * 16;
  char* la1 = (char*)As + c1 * 16;
  char* lb0 = (char*)Bs + c0 * 16;
  char* lb1 = (char*)Bs + c1 * 16;

  for (int kt = 0; kt < DM; kt += 32) {
    gl2lds16(xa0 + kt, la0);
    gl2lds16(xa1 + kt, la1);
    gl2lds16(wb0 + kt, lb0);
    gl2lds16(wb1 + kt, lb1);
    __syncthreads();

    bf16x8 a[4], b[4];
    #pragma unroll
    for (int t = 0; t < 4; ++t)
      a[t] = *(const bf16x8*)(As + (wm * 64 + t * 16 + fr) * 32 + quad * 8);
    #pragma unroll
    for (int t = 0; t < 4; ++t)
      b[t] = *(const bf16x8*)(Bs + (wn * 64 + t * 16 + fr) * 32 + quad * 8);

    #pragma unroll
    for (int i = 0; i < 4; ++i)
      #pragma unroll
      for (int j = 0; j < 4; ++j)
        acc[i][j] = __builtin_amdgcn_mfma_f32_16x16x32_bf16(a[i], b[j], acc[i][j], 0, 0, 0);
    __syncthreads();
  }
}

// QKV projection: grid (32, 24); y>>3 selects weight, y&7 the col-block.
// Q,K stored [H][L][64]; V stored transposed [H][64][L]
__global__ __launch_bounds__(256) void qkv_gemm(
    const unsigned short* __restrict__ X,
    const unsigned short* __restrict__ Wq,
    const unsigned short* __restrict__ Wk,
    const unsigned short* __restrict__ Wv,
    unsigned short* __restrict__ Qo,
    unsigned short* __restrict__ Ko,
    unsigned short* __restrict__ Vt)
{
  __shared__ unsigned short As[128 * 32];
  __shared__ unsigned short Bs[128 * 32];
  const int m0   = blockIdx.x * 128;
  const int wsel = blockIdx.y >> 3;
  const int n0   = (blockIdx.y & 7) * 128;
  const unsigned short* W = (wsel == 0) ? Wq : (wsel == 1) ? Wk : Wv;

  f32x4 acc[4][4];
  gemm_tile(X, W, m0, n0, As, Bs, acc);

  const int lane = threadIdx.x & 63;
  const int wave = threadIdx.x >> 6;
  const int wm = wave >> 1, wn = wave & 1;
  const int cn = lane & 15, quad = lane >> 4;
  #pragma unroll
  for (int i = 0; i < 4; ++i)
    #pragma unroll
    for (int j = 0; j < 4; ++j)
      #pragma unroll
      for (int r = 0; r < 4; ++r) {
        const int row = m0 + wm * 64 + i * 16 + quad * 4 + r;
        const int col = n0 + wn * 64 + j * 16 + cn;
        const int h = col >> 6, d = col & 63;
        const unsigned short v = f2bf(acc[i][j][r]);
        if (wsel == 2)      Vt[(size_t)(h * DH + d) * LSEQ + row] = v;
        else if (wsel == 1) Ko[(size_t)(h * LSEQ + row) * DH + d] = v;
        else                Qo[(size_t)(h * LSEQ + row) * DH + d] = v;
      }
}

// Output projection: grid (32, 8): out[L][DM] = Attn * Wo^T  -- fp32 store
__global__ __launch_bounds__(256) void out_gemm(
    const unsigned short* __restrict__ X,
    const unsigned short* __restrict__ W,
    float* __restrict__ O)
{
  __shared__ unsigned short As[128 * 32];
  __shared__ unsigned short Bs[128 * 32];
  const int m0 = blockIdx.x * 128;
  const int n0 = blockIdx.y * 128;

  f32x4 acc[4][4];
  gemm_tile(X, W, m0, n0, As, Bs, acc);

  const int lane = threadIdx.x & 63;
  const int wave = threadIdx.x >> 6;
  const int wm = wave >> 1, wn = wave & 1;
  const int cn = lane & 15, quad = lane >> 4;
  #pragma unroll
  for (int i = 0; i < 4; ++i)
    #pragma unroll
    for (int j = 0; j < 4; ++j)
      #pragma unroll
      for (int r = 0; r < 4; ++r) {
        const int row = m0 + wm * 64 + i * 16 + quad * 4 + r;
        const int col = n0 + wn * 64 + j * 16 + cn;
        O[(size_t)row * DM + col] = acc[i][j][r];
      }
}

// Flash sliding-window attention. grid (L/64, H), 256 threads.
// Validated (R2==R4 bit-match). wave = 16 queries; 32-key steps.
__global__ __launch_bounds__(256) void attn_fwd(
    const unsigned short* __restrict__ Q,
    const unsigned short* __restrict__ K,
    const unsigned short* __restrict__ Vt,
    unsigned short* __restrict__ Oa)
{
  __shared__ unsigned short Pl[4][16 * 32];
  const int h    = blockIdx.y;
  const int bq0  = blockIdx.x * 64;
  const int wave = threadIdx.x >> 6;
  const int lane = threadIdx.x & 63;
  const int n = lane & 15, quad = lane >> 4;
  const int q0 = bq0 + wave * 16;
  unsigned short* pl = Pl[wave];
  const float scale = 0.125f;   // 1/sqrt(64)

  const size_t qbase = ((size_t)(h * LSEQ + q0 + n)) * DH + quad * 8;
  const bf16x8 aq0 = *(const bf16x8*)(Q + qbase);
  const bf16x8 aq1 = *(const bf16x8*)(Q + qbase + 32);

  const f32x4 zero = {0.f, 0.f, 0.f, 0.f};
  f32x4 acc[4] = {zero, zero, zero, zero};
  float mi[4], li[4];
  #pragma unroll
  for (int r = 0; r < 4; ++r) { mi[r] = -1e28f; li[r] = 0.f; }

  const int jb0 = (bq0 >= WIN) ? ((bq0 - WIN + 1) & ~31) : 0;
  for (int jb = jb0; jb < bq0 + 64; jb += 32) {
    f32x4 s[2];
    #pragma unroll
    for (int u = 0; u < 2; ++u) {
      const int j0 = jb + u * 16;
      const size_t kbase = ((size_t)(h * LSEQ + j0 + n)) * DH + quad * 8;
      const bf16x8 kb0 = *(const bf16x8*)(K + kbase);
      const bf16x8 kb1 = *(const bf16x8*)(K + kbase + 32);
      f32x4 c = zero;
      c = __builtin_amdgcn_mfma_f32_16x16x32_bf16(aq0, kb0, c, 0, 0, 0);
      c = __builtin_amdgcn_mfma_f32_16x16x32_bf16(aq1, kb1, c, 0, 0, 0);
      #pragma unroll
      for (int r = 0; r < 4; ++r) {
        const int qi = q0 + quad * 4 + r;
        const int kj = j0 + n;
        const bool ok = (kj <= qi) && (kj + WIN > qi);
        s[u][r] = ok ? c[r] * scale : -1e30f;
      }
    }
    float alpha[4];
    #pragma unroll
    for (int r = 0; r < 4; ++r) {
      float v = fmaxf(s[0][r], s[1][r]);
      v = fmaxf(v, __shfl_xor(v, 1));
      v = fmaxf(v, __shfl_xor(v, 2));
      v = fmaxf(v, __shfl_xor(v, 4));
      v = fmaxf(v, __shfl_xor(v, 8));
      const float mn = fmaxf(mi[r], v);
      alpha[r] = __expf(mi[r] - mn);
      mi[r] = mn;
    }
    #pragma unroll
    for (int u = 0; u < 2; ++u)
      #pragma unroll
      for (int r = 0; r < 4; ++r)
        s[u][r] = __expf(s[u][r] - mi[r]);
    #pragma unroll
    for (int r = 0; r < 4; ++r) {
      float v = s[0][r] + s[1][r];
      v += __shfl_xor(v, 1);
      v += __shfl_xor(v, 2);
      v += __shfl_xor(v, 4);
      v += __shfl_xor(v, 8);
      li[r] = li[r] * alpha[r] + v;
      acc[0][r] *= alpha[r];
      acc[1][r] *= alpha[r];
      acc[2][r] *= alpha[r];
      acc[3][r] *= alpha[r];
    }
    #pragma unroll
    for (int u = 0; u < 2; ++u)
      #pragma unroll
      for (int r = 0; r < 4; ++r)
        pl[(quad * 4 + r) * 32 + u * 16 + n] = f2bf(s[u][r]);
    __syncthreads();
    const bf16x8 pa = *(const bf16x8*)(pl + n * 32 + quad * 8);
    #pragma unroll
    for (int ct = 0; ct < 4; ++ct) {
      const bf16x8 vb =
          *(const bf16x8*)(Vt + ((size_t)(h * DH + ct * 16 + n)) * LSEQ + jb + quad * 8);
      acc[ct] = __builtin_amdgcn_mfma_f32_16x16x32_bf16(pa, vb, acc[ct], 0, 0, 0);
    }
    __syncthreads();
  }

  #pragma unroll
  for (int ct = 0; ct < 4; ++ct)
    #pragma unroll
    for (int r = 0; r < 4; ++r) {
      const int row = q0 + quad * 4 + r;
      const int col = h * DH + ct * 16 + n;
      Oa[(size_t)row * DM + col] = f2bf(acc[ct][r] / li[r]);
    }
}

extern "C" void kernel_launch(void* const* d_in, const int* in_sizes, int n_in,
                              void* d_out, int out_size, void* d_ws, size_t ws_size,
                              hipStream_t stream) {
  const float* x  = (const float*)d_in[0];
  const float* Wq = (const float*)d_in[1];
  const float* Wk = (const float*)d_in[2];
  const float* Wv = (const float*)d_in[3];
  const float* Wo = (const float*)d_in[4];
  float* out = (float*)d_out;               // fp32 output (proven R6)

  unsigned short* xb  = (unsigned short*)d_ws;            // [L][DM]    8 MiB
  unsigned short* Wqb = xb  + (size_t)LSEQ * DM;          // 2 MiB each
  unsigned short* Wkb = Wqb + (size_t)DM * DM;
  unsigned short* Wvb = Wkb + (size_t)DM * DM;
  unsigned short* Wob = Wvb + (size_t)DM * DM;
  unsigned short* Q    = Wob + (size_t)DM * DM;           // [H][L][64] 8 MiB
  unsigned short* K    = Q   + (size_t)LSEQ * DM;
  unsigned short* Vt   = K   + (size_t)LSEQ * DM;         // [H][64][L]
  unsigned short* Attn = Vt  + (size_t)LSEQ * DM;         // [L][DM]
  // total: 48 MiB (ws >= 64 MiB, proven R4)

  cvt5<<<dim3(2048, 5), 256, 0, stream>>>(x, Wq, Wk, Wv, Wo, xb, Wqb, Wkb, Wvb, Wob);
  qkv_gemm<<<dim3(32, 24), 256, 0, stream>>>(xb, Wqb, Wkb, Wvb, Q, K, Vt);
  attn_fwd<<<dim3(64, 16), 256, 0, stream>>>(Q, K, Vt, Attn);
  out_gemm<<<dim3(32, 8), 256, 0, stream>>>(Attn, Wob, out);
}

// Round 8
// 196.231 us; speedup vs baseline: 8.7041x; 1.0388x over previous
//
#include <hip/hip_runtime.h>

using bf16x8 = __attribute__((ext_vector_type(8))) short;
using u16x8  = __attribute__((ext_vector_type(8))) unsigned short;
using f32x4  = __attribute__((ext_vector_type(4))) float;

#define LSEQ   4096
#define NH     16
#define DH     64
#define WIN    256
#define DM     1024

// async global->LDS, 16B per lane; LDS dest is wave-uniform base + lane*16
__device__ __forceinline__ void gl2lds16(const void* g, void* l) {
  __builtin_amdgcn_global_load_lds(
      (const __attribute__((address_space(1))) unsigned int*)g,
      (__attribute__((address_space(3))) unsigned int*)l,
      16, 0, 0);
}

// fp32 -> bf16 RNE (finite inputs only)
__device__ __forceinline__ unsigned short f2bf(float f) {
  unsigned int u = __float_as_uint(f);
  u += 0x7fffu + ((u >> 16) & 1u);
  return (unsigned short)(u >> 16);
}

// ---- fp32 -> bf16 conversion of x and the 4 weight matrices --------------
__global__ __launch_bounds__(256) void cvt5(
    const float* __restrict__ p0, const float* __restrict__ p1,
    const float* __restrict__ p2, const float* __restrict__ p3,
    const float* __restrict__ p4,
    unsigned short* __restrict__ q0, unsigned short* __restrict__ q1,
    unsigned short* __restrict__ q2, unsigned short* __restrict__ q3,
    unsigned short* __restrict__ q4)
{
  const int seg = blockIdx.y;
  const float* src = (seg == 0) ? p0 : (seg == 1) ? p1 : (seg == 2) ? p2
                     : (seg == 3) ? p3 : p4;
  unsigned short* dst = (seg == 0) ? q0 : (seg == 1) ? q1 : (seg == 2) ? q2
                        : (seg == 3) ? q3 : q4;
  const int n = (seg == 0) ? (LSEQ * DM) : (DM * DM);
  const int i = (blockIdx.x * 256 + threadIdx.x) * 8;
  if (i >= n) return;
  const f32x4 f0 = *(const f32x4*)(src + i);
  const f32x4 f1 = *(const f32x4*)(src + i + 4);
  u16x8 o;
  o[0] = f2bf(f0[0]); o[1] = f2bf(f0[1]); o[2] = f2bf(f0[2]); o[3] = f2bf(f0[3]);
  o[4] = f2bf(f1[0]); o[5] = f2bf(f1[1]); o[6] = f2bf(f1[2]); o[7] = f2bf(f1[3]);
  *(u16x8*)(dst + i) = o;
}

// 128x128 NT GEMM tile (validated R2==R4): global_load_lds + 16x16x32 MFMA
__device__ __forceinline__ void gemm_tile(
    const unsigned short* __restrict__ X,
    const unsigned short* __restrict__ W,
    int m0, int n0,
    unsigned short* As, unsigned short* Bs,
    f32x4 (&acc)[4][4])
{
  const int tid  = threadIdx.x;
  const int lane = tid & 63;
  const int wave = tid >> 6;
  const int wm = wave >> 1, wn = wave & 1;
  const int fr = lane & 15, quad = lane >> 4;

  const f32x4 zero = {0.f, 0.f, 0.f, 0.f};
  #pragma unroll
  for (int i = 0; i < 4; ++i)
    #pragma unroll
    for (int j = 0; j < 4; ++j)
      acc[i][j] = zero;

  const int c0 = tid, c1 = tid + 256;
  const unsigned short* xa0 = X + (size_t)(m0 + (c0 >> 2)) * DM + (c0 & 3) * 8;
  const unsigned short* xa1 = X + (size_t)(m0 + (c1 >> 2)) * DM + (c1 & 3) * 8;
  const unsigned short* wb0 = W + (size_t)(n0 + (c0 >> 2)) * DM + (c0 & 3) * 8;
  const unsigned short* wb1 = W + (size_t)(n0 + (c1 >> 2)) * DM + (c1 & 3) * 8;
  char* la0 = (char*)As + c0 * 16;
  char* la1 = (char*)As + c1 * 16;
  char* lb0 = (char*)Bs + c0 * 16;
  char* lb1 = (char*)Bs + c1 * 16;

  for (int kt = 0; kt < DM; kt += 32) {
    gl2lds16(xa0 + kt, la0);
    gl2lds16(xa1 + kt, la1);
    gl2lds16(wb0 + kt, lb0);
    gl2lds16(wb1 + kt, lb1);
    __syncthreads();

    bf16x8 a[4], b[4];
    #pragma unroll
    for (int t = 0; t < 4; ++t)
      a[t] = *(const bf16x8*)(As + (wm * 64 + t * 16 + fr) * 32 + quad * 8);
    #pragma unroll
    for (int t = 0; t < 4; ++t)
      b[t] = *(const bf16x8*)(Bs + (wn * 64 + t * 16 + fr) * 32 + quad * 8);

    #pragma unroll
    for (int i = 0; i < 4; ++i)
      #pragma unroll
      for (int j = 0; j < 4; ++j)
        acc[i][j] = __builtin_amdgcn_mfma_f32_16x16x32_bf16(a[i], b[j], acc[i][j], 0, 0, 0);
    __syncthreads();
  }
}

// QKV projection: grid (32, 24). Q,K: [H][L][64]; V transposed: [H][64][L]
__global__ __launch_bounds__(256) void qkv_gemm(
    const unsigned short* __restrict__ X,
    const unsigned short* __restrict__ Wq,
    const unsigned short* __restrict__ Wk,
    const unsigned short* __restrict__ Wv,
    unsigned short* __restrict__ Qo,
    unsigned short* __restrict__ Ko,
    unsigned short* __restrict__ Vt)
{
  __shared__ unsigned short As[128 * 32];
  __shared__ unsigned short Bs[128 * 32];
  const int m0   = blockIdx.x * 128;
  const int wsel = blockIdx.y >> 3;
  const int n0   = (blockIdx.y & 7) * 128;
  const unsigned short* W = (wsel == 0) ? Wq : (wsel == 1) ? Wk : Wv;

  f32x4 acc[4][4];
  gemm_tile(X, W, m0, n0, As, Bs, acc);

  const int lane = threadIdx.x & 63;
  const int wave = threadIdx.x >> 6;
  const int wm = wave >> 1, wn = wave & 1;
  const int cn = lane & 15, quad = lane >> 4;
  #pragma unroll
  for (int i = 0; i < 4; ++i)
    #pragma unroll
    for (int j = 0; j < 4; ++j)
      #pragma unroll
      for (int r = 0; r < 4; ++r) {
        const int row = m0 + wm * 64 + i * 16 + quad * 4 + r;
        const int col = n0 + wn * 64 + j * 16 + cn;
        const int h = col >> 6, d = col & 63;
        const unsigned short v = f2bf(acc[i][j][r]);
        if (wsel == 2)      Vt[(size_t)(h * DH + d) * LSEQ + row] = v;
        else if (wsel == 1) Ko[(size_t)(h * LSEQ + row) * DH + d] = v;
        else                Qo[(size_t)(h * LSEQ + row) * DH + d] = v;
      }
}

// Output projection, 64x128 tiles for 2 blocks/CU: grid (64, 8), fp32 store
__global__ __launch_bounds__(256) void out_gemm(
    const unsigned short* __restrict__ X,
    const unsigned short* __restrict__ W,
    float* __restrict__ O)
{
  __shared__ unsigned short As2[64 * 32];
  __shared__ unsigned short Bs[128 * 32];
  const int m0 = blockIdx.x * 64;
  const int n0 = blockIdx.y * 128;
  const int tid  = threadIdx.x;
  const int lane = tid & 63;
  const int wave = tid >> 6;
  const int wm = wave >> 1, wn = wave & 1;
  const int fr = lane & 15, quad = lane >> 4;

  const f32x4 zero = {0.f, 0.f, 0.f, 0.f};
  f32x4 acc[2][4];
  #pragma unroll
  for (int i = 0; i < 2; ++i)
    #pragma unroll
    for (int j = 0; j < 4; ++j)
      acc[i][j] = zero;

  // A: 256 chunks (64 rows x 4); B: 512 chunks (128 rows x 4)
  const unsigned short* xa  = X + (size_t)(m0 + (tid >> 2)) * DM + (tid & 3) * 8;
  const unsigned short* wb0 = W + (size_t)(n0 + (tid >> 2)) * DM + (tid & 3) * 8;
  const unsigned short* wb1 = W + (size_t)(n0 + ((tid + 256) >> 2)) * DM + (tid & 3) * 8;
  char* la  = (char*)As2 + tid * 16;
  char* lb0 = (char*)Bs + tid * 16;
  char* lb1 = (char*)Bs + (tid + 256) * 16;

  for (int kt = 0; kt < DM; kt += 32) {
    gl2lds16(xa + kt, la);
    gl2lds16(wb0 + kt, lb0);
    gl2lds16(wb1 + kt, lb1);
    __syncthreads();

    bf16x8 a[2], b[4];
    #pragma unroll
    for (int t = 0; t < 2; ++t)
      a[t] = *(const bf16x8*)(As2 + (wm * 32 + t * 16 + fr) * 32 + quad * 8);
    #pragma unroll
    for (int t = 0; t < 4; ++t)
      b[t] = *(const bf16x8*)(Bs + (wn * 64 + t * 16 + fr) * 32 + quad * 8);

    #pragma unroll
    for (int i = 0; i < 2; ++i)
      #pragma unroll
      for (int j = 0; j < 4; ++j)
        acc[i][j] = __builtin_amdgcn_mfma_f32_16x16x32_bf16(a[i], b[j], acc[i][j], 0, 0, 0);
    __syncthreads();
  }

  const int cn = lane & 15;
  #pragma unroll
  for (int i = 0; i < 2; ++i)
    #pragma unroll
    for (int j = 0; j < 4; ++j)
      #pragma unroll
      for (int r = 0; r < 4; ++r) {
        const int row = m0 + wm * 32 + i * 16 + quad * 4 + r;
        const int col = n0 + wn * 64 + j * 16 + cn;
        O[(size_t)row * DM + col] = acc[i][j][r];
      }
}

// Flash sliding-window attention, barrier-free (per-wave LDS only).
// grid (L/64, H), 256 threads; wave = 16 queries; 64-key steps.
#define PSTR 80   // P-tile row stride (elems): 160B, 16B-aligned frags
__global__ __launch_bounds__(256) void attn_fwd(
    const unsigned short* __restrict__ Q,
    const unsigned short* __restrict__ K,
    const unsigned short* __restrict__ Vt,
    unsigned short* __restrict__ Oa)
{
  __shared__ unsigned short Pl[4][16 * PSTR];
  const int h    = blockIdx.y;
  const int bq0  = blockIdx.x * 64;
  const int wave = threadIdx.x >> 6;
  const int lane = threadIdx.x & 63;
  const int n = lane & 15, quad = lane >> 4;
  const int q0 = bq0 + wave * 16;
  unsigned short* pl = Pl[wave];
  const float scl = 0.125f * 1.44269504f;   // 1/sqrt(64) * log2(e); exp2 softmax

  const size_t qbase = ((size_t)(h * LSEQ + q0 + n)) * DH + quad * 8;
  const bf16x8 aq0 = *(const bf16x8*)(Q + qbase);
  const bf16x8 aq1 = *(const bf16x8*)(Q + qbase + 32);

  const f32x4 zero = {0.f, 0.f, 0.f, 0.f};
  f32x4 acc[4] = {zero, zero, zero, zero};
  float mi[4], li[4];
  #pragma unroll
  for (int r = 0; r < 4; ++r) { mi[r] = -1e28f; li[r] = 0.f; }

  const int jb0 = (bq0 >= WIN) ? (bq0 - WIN) : 0;   // multiple of 64
  for (int jb = jb0; jb < bq0 + 64; jb += 64) {
    // ---- scores for 4 x 16-key subtiles (64 keys)
    f32x4 s[4];
    #pragma unroll
    for (int u = 0; u < 4; ++u) {
      const int j0 = jb + u * 16;
      const size_t kbase = ((size_t)(h * LSEQ + j0 + n)) * DH + quad * 8;
      const bf16x8 kb0 = *(const bf16x8*)(K + kbase);
      const bf16x8 kb1 = *(const bf16x8*)(K + kbase + 32);
      f32x4 c = zero;
      c = __builtin_amdgcn_mfma_f32_16x16x32_bf16(aq0, kb0, c, 0, 0, 0);
      c = __builtin_amdgcn_mfma_f32_16x16x32_bf16(aq1, kb1, c, 0, 0, 0);
      #pragma unroll
      for (int r = 0; r < 4; ++r) {
        const int qi = q0 + quad * 4 + r;
        const int kj = j0 + n;
        const bool ok = (kj <= qi) && (kj + WIN > qi);
        s[u][r] = ok ? c[r] * scl : -1e30f;
      }
    }
    // ---- online softmax (base-2), stats across 16 lanes per quad-row
    float alpha[4];
    #pragma unroll
    for (int r = 0; r < 4; ++r) {
      float v = fmaxf(fmaxf(s[0][r], s[1][r]), fmaxf(s[2][r], s[3][r]));
      v = fmaxf(v, __shfl_xor(v, 1));
      v = fmaxf(v, __shfl_xor(v, 2));
      v = fmaxf(v, __shfl_xor(v, 4));
      v = fmaxf(v, __shfl_xor(v, 8));
      const float mn = fmaxf(mi[r], v);
      alpha[r] = __builtin_exp2f(mi[r] - mn);
      mi[r] = mn;
    }
    #pragma unroll
    for (int u = 0; u < 4; ++u)
      #pragma unroll
      for (int r = 0; r < 4; ++r)
        s[u][r] = __builtin_exp2f(s[u][r] - mi[r]);
    #pragma unroll
    for (int r = 0; r < 4; ++r) {
      float v = (s[0][r] + s[1][r]) + (s[2][r] + s[3][r]);
      v += __shfl_xor(v, 1);
      v += __shfl_xor(v, 2);
      v += __shfl_xor(v, 4);
      v += __shfl_xor(v, 8);
      li[r] = li[r] * alpha[r] + v;
      acc[0][r] *= alpha[r];
      acc[1][r] *= alpha[r];
      acc[2][r] *= alpha[r];
      acc[3][r] *= alpha[r];
    }
    // ---- P: C-layout regs -> per-wave LDS -> A-operand layout (no barrier)
    #pragma unroll
    for (int u = 0; u < 4; ++u)
      #pragma unroll
      for (int r = 0; r < 4; ++r)
        pl[(quad * 4 + r) * PSTR + u * 16 + n] = f2bf(s[u][r]);
    asm volatile("s_waitcnt lgkmcnt(0)" ::: "memory");   // wave-private LDS fence
    const bf16x8 pa0 = *(const bf16x8*)(pl + n * PSTR + quad * 8);
    const bf16x8 pa1 = *(const bf16x8*)(pl + n * PSTR + 32 + quad * 8);
    // ---- PV: B-operand from V^T [H][64][L]
    #pragma unroll
    for (int ct = 0; ct < 4; ++ct) {
      const size_t vb = ((size_t)(h * DH + ct * 16 + n)) * LSEQ + jb + quad * 8;
      const bf16x8 vb0 = *(const bf16x8*)(Vt + vb);
      const bf16x8 vb1 = *(const bf16x8*)(Vt + vb + 32);
      acc[ct] = __builtin_amdgcn_mfma_f32_16x16x32_bf16(pa0, vb0, acc[ct], 0, 0, 0);
      acc[ct] = __builtin_amdgcn_mfma_f32_16x16x32_bf16(pa1, vb1, acc[ct], 0, 0, 0);
    }
  }

  #pragma unroll
  for (int ct = 0; ct < 4; ++ct)
    #pragma unroll
    for (int r = 0; r < 4; ++r) {
      const int row = q0 + quad * 4 + r;
      const int col = h * DH + ct * 16 + n;
      Oa[(size_t)row * DM + col] = f2bf(acc[ct][r] / li[r]);
    }
}

extern "C" void kernel_launch(void* const* d_in, const int* in_sizes, int n_in,
                              void* d_out, int out_size, void* d_ws, size_t ws_size,
                              hipStream_t stream) {
  const float* x  = (const float*)d_in[0];
  const float* Wq = (const float*)d_in[1];
  const float* Wk = (const float*)d_in[2];
  const float* Wv = (const float*)d_in[3];
  const float* Wo = (const float*)d_in[4];
  float* out = (float*)d_out;               // fp32 output (proven R6)

  unsigned short* xb  = (unsigned short*)d_ws;            // [L][DM]    8 MiB
  unsigned short* Wqb = xb  + (size_t)LSEQ * DM;          // 2 MiB each
  unsigned short* Wkb = Wqb + (size_t)DM * DM;
  unsigned short* Wvb = Wkb + (size_t)DM * DM;
  unsigned short* Wob = Wvb + (size_t)DM * DM;
  unsigned short* Q    = Wob + (size_t)DM * DM;           // [H][L][64] 8 MiB
  unsigned short* K    = Q   + (size_t)LSEQ * DM;
  unsigned short* Vt   = K   + (size_t)LSEQ * DM;         // [H][64][L]
  unsigned short* Attn = Vt  + (size_t)LSEQ * DM;         // [L][DM]
  // total 48 MiB (ws >= 64 MiB, proven R4)

  cvt5<<<dim3(2048, 5), 256, 0, stream>>>(x, Wq, Wk, Wv, Wo, xb, Wqb, Wkb, Wvb, Wob);
  qkv_gemm<<<dim3(32, 24), 256, 0, stream>>>(xb, Wqb, Wkb, Wvb, Q, K, Vt);
  attn_fwd<<<dim3(64, 16), 256, 0, stream>>>(Q, K, Vt, Attn);
  out_gemm<<<dim3(64, 8), 256, 0, stream>>>(Attn, Wob, out);
}

// Round 9
// 191.584 us; speedup vs baseline: 8.9153x; 1.0243x over previous
//
#include <hip/hip_runtime.h>

using bf16x8 = __attribute__((ext_vector_type(8))) short;
using u16x8  = __attribute__((ext_vector_type(8))) unsigned short;
using f32x4  = __attribute__((ext_vector_type(4))) float;

#define LSEQ   4096
#define NH     16
#define DH     64
#define WIN    256
#define DM     1024

// async global->LDS, 16B per lane; LDS dest is wave-uniform base + lane*16
__device__ __forceinline__ void gl2lds16(const void* g, void* l) {
  __builtin_amdgcn_global_load_lds(
      (const __attribute__((address_space(1))) unsigned int*)g,
      (__attribute__((address_space(3))) unsigned int*)l,
      16, 0, 0);
}

// fp32 -> bf16 RNE (finite inputs only)
__device__ __forceinline__ unsigned short f2bf(float f) {
  unsigned int u = __float_as_uint(f);
  u += 0x7fffu + ((u >> 16) & 1u);
  return (unsigned short)(u >> 16);
}

// ---- fp32 -> bf16 conversion of x and the 4 weight matrices --------------
__global__ __launch_bounds__(256) void cvt5(
    const float* __restrict__ p0, const float* __restrict__ p1,
    const float* __restrict__ p2, const float* __restrict__ p3,
    const float* __restrict__ p4,
    unsigned short* __restrict__ q0, unsigned short* __restrict__ q1,
    unsigned short* __restrict__ q2, unsigned short* __restrict__ q3,
    unsigned short* __restrict__ q4)
{
  const int seg = blockIdx.y;
  const float* src = (seg == 0) ? p0 : (seg == 1) ? p1 : (seg == 2) ? p2
                     : (seg == 3) ? p3 : p4;
  unsigned short* dst = (seg == 0) ? q0 : (seg == 1) ? q1 : (seg == 2) ? q2
                        : (seg == 3) ? q3 : q4;
  const int n = (seg == 0) ? (LSEQ * DM) : (DM * DM);
  const int i = (blockIdx.x * 256 + threadIdx.x) * 8;
  if (i >= n) return;
  const f32x4 f0 = *(const f32x4*)(src + i);
  const f32x4 f1 = *(const f32x4*)(src + i + 4);
  u16x8 o;
  o[0] = f2bf(f0[0]); o[1] = f2bf(f0[1]); o[2] = f2bf(f0[2]); o[3] = f2bf(f0[3]);
  o[4] = f2bf(f1[0]); o[5] = f2bf(f1[1]); o[6] = f2bf(f1[2]); o[7] = f2bf(f1[3]);
  *(u16x8*)(dst + i) = o;
}

// 128x128 NT GEMM tile (validated R2==R4): global_load_lds + 16x16x32 MFMA
__device__ __forceinline__ void gemm_tile(
    const unsigned short* __restrict__ X,
    const unsigned short* __restrict__ W,
    int m0, int n0,
    unsigned short* As, unsigned short* Bs,
    f32x4 (&acc)[4][4])
{
  const int tid  = threadIdx.x;
  const int lane = tid & 63;
  const int wave = tid >> 6;
  const int wm = wave >> 1, wn = wave & 1;
  const int fr = lane & 15, quad = lane >> 4;

  const f32x4 zero = {0.f, 0.f, 0.f, 0.f};
  #pragma unroll
  for (int i = 0; i < 4; ++i)
    #pragma unroll
    for (int j = 0; j < 4; ++j)
      acc[i][j] = zero;

  const int c0 = tid, c1 = tid + 256;
  const unsigned short* xa0 = X + (size_t)(m0 + (c0 >> 2)) * DM + (c0 & 3) * 8;
  const unsigned short* xa1 = X + (size_t)(m0 + (c1 >> 2)) * DM + (c1 & 3) * 8;
  const unsigned short* wb0 = W + (size_t)(n0 + (c0 >> 2)) * DM + (c0 & 3) * 8;
  const unsigned short* wb1 = W + (size_t)(n0 + (c1 >> 2)) * DM + (c1 & 3) * 8;
  char* la0 = (char*)As + c0 * 16;
  char* la1 = (char*)As + c1 * 16;
  char* lb0 = (char*)Bs + c0 * 16;
  char* lb1 = (char*)Bs + c1 * 16;

  for (int kt = 0; kt < DM; kt += 32) {
    gl2lds16(xa0 + kt, la0);
    gl2lds16(xa1 + kt, la1);
    gl2lds16(wb0 + kt, lb0);
    gl2lds16(wb1 + kt, lb1);
    __syncthreads();

    bf16x8 a[4], b[4];
    #pragma unroll
    for (int t = 0; t < 4; ++t)
      a[t] = *(const bf16x8*)(As + (wm * 64 + t * 16 + fr) * 32 + quad * 8);
    #pragma unroll
    for (int t = 0; t < 4; ++t)
      b[t] = *(const bf16x8*)(Bs + (wn * 64 + t * 16 + fr) * 32 + quad * 8);

    #pragma unroll
    for (int i = 0; i < 4; ++i)
      #pragma unroll
      for (int j = 0; j < 4; ++j)
        acc[i][j] = __builtin_amdgcn_mfma_f32_16x16x32_bf16(a[i], b[j], acc[i][j], 0, 0, 0);
    __syncthreads();
  }
}

// Q,K projection: grid (32, 16); y>>3 selects weight, y&7 the col-block.
// Q,K stored [H][L][64]
__global__ __launch_bounds__(256) void qk_gemm(
    const unsigned short* __restrict__ X,
    const unsigned short* __restrict__ Wq,
    const unsigned short* __restrict__ Wk,
    unsigned short* __restrict__ Qo,
    unsigned short* __restrict__ Ko)
{
  __shared__ unsigned short As[128 * 32];
  __shared__ unsigned short Bs[128 * 32];
  const int m0   = blockIdx.x * 128;
  const int wsel = blockIdx.y >> 3;
  const int n0   = (blockIdx.y & 7) * 128;
  const unsigned short* W = wsel ? Wk : Wq;
  unsigned short* O = wsel ? Ko : Qo;

  f32x4 acc[4][4];
  gemm_tile(X, W, m0, n0, As, Bs, acc);

  const int lane = threadIdx.x & 63;
  const int wave = threadIdx.x >> 6;
  const int wm = wave >> 1, wn = wave & 1;
  const int cn = lane & 15, quad = lane >> 4;
  #pragma unroll
  for (int i = 0; i < 4; ++i)
    #pragma unroll
    for (int j = 0; j < 4; ++j)
      #pragma unroll
      for (int r = 0; r < 4; ++r) {
        const int row = m0 + wm * 64 + i * 16 + quad * 4 + r;
        const int col = n0 + wn * 64 + j * 16 + cn;
        const int h = col >> 6, d = col & 63;
        O[(size_t)(h * LSEQ + row) * DH + d] = f2bf(acc[i][j][r]);
      }
}

// V^T by operand swap: C^T[d][tok] = sum_k Wv[d][k] * X[tok][k].
// A-tile = Wv rows (output rows = d), B-tile = X rows (cols = token).
// C-layout: col (lane&15) = token -> Vt stores are 32B-contiguous per quad.
// grid (8, 32): m0 = d-block, n0 = token-block. Vt = [H*DH][L].
__global__ __launch_bounds__(256) void v_gemm_t(
    const unsigned short* __restrict__ X,
    const unsigned short* __restrict__ Wv,
    unsigned short* __restrict__ Vt)
{
  __shared__ unsigned short As[128 * 32];
  __shared__ unsigned short Bs[128 * 32];
  const int m0 = blockIdx.x * 128;   // d
  const int n0 = blockIdx.y * 128;   // tokens

  f32x4 acc[4][4];
  gemm_tile(Wv, X, m0, n0, As, Bs, acc);

  const int lane = threadIdx.x & 63;
  const int wave = threadIdx.x >> 6;
  const int wm = wave >> 1, wn = wave & 1;
  const int cn = lane & 15, quad = lane >> 4;
  #pragma unroll
  for (int i = 0; i < 4; ++i)
    #pragma unroll
    for (int j = 0; j < 4; ++j)
      #pragma unroll
      for (int r = 0; r < 4; ++r) {
        const int row = m0 + wm * 64 + i * 16 + quad * 4 + r;   // d-dim (H*DH)
        const int col = n0 + wn * 64 + j * 16 + cn;             // token
        Vt[(size_t)row * LSEQ + col] = f2bf(acc[i][j][r]);
      }
}

// Output projection, 64x128 tiles: grid (64, 8), fp32 store
__global__ __launch_bounds__(256) void out_gemm(
    const unsigned short* __restrict__ X,
    const unsigned short* __restrict__ W,
    float* __restrict__ O)
{
  __shared__ unsigned short As2[64 * 32];
  __shared__ unsigned short Bs[128 * 32];
  const int m0 = blockIdx.x * 64;
  const int n0 = blockIdx.y * 128;
  const int tid  = threadIdx.x;
  const int lane = tid & 63;
  const int wave = tid >> 6;
  const int wm = wave >> 1, wn = wave & 1;
  const int fr = lane & 15, quad = lane >> 4;

  const f32x4 zero = {0.f, 0.f, 0.f, 0.f};
  f32x4 acc[2][4];
  #pragma unroll
  for (int i = 0; i < 2; ++i)
    #pragma unroll
    for (int j = 0; j < 4; ++j)
      acc[i][j] = zero;

  const unsigned short* xa  = X + (size_t)(m0 + (tid >> 2)) * DM + (tid & 3) * 8;
  const unsigned short* wb0 = W + (size_t)(n0 + (tid >> 2)) * DM + (tid & 3) * 8;
  const unsigned short* wb1 = W + (size_t)(n0 + ((tid + 256) >> 2)) * DM + (tid & 3) * 8;
  char* la  = (char*)As2 + tid * 16;
  char* lb0 = (char*)Bs + tid * 16;
  char* lb1 = (char*)Bs + (tid + 256) * 16;

  for (int kt = 0; kt < DM; kt += 32) {
    gl2lds16(xa + kt, la);
    gl2lds16(wb0 + kt, lb0);
    gl2lds16(wb1 + kt, lb1);
    __syncthreads();

    bf16x8 a[2], b[4];
    #pragma unroll
    for (int t = 0; t < 2; ++t)
      a[t] = *(const bf16x8*)(As2 + (wm * 32 + t * 16 + fr) * 32 + quad * 8);
    #pragma unroll
    for (int t = 0; t < 4; ++t)
      b[t] = *(const bf16x8*)(Bs + (wn * 64 + t * 16 + fr) * 32 + quad * 8);

    #pragma unroll
    for (int i = 0; i < 2; ++i)
      #pragma unroll
      for (int j = 0; j < 4; ++j)
        acc[i][j] = __builtin_amdgcn_mfma_f32_16x16x32_bf16(a[i], b[j], acc[i][j], 0, 0, 0);
    __syncthreads();
  }

  const int cn = lane & 15;
  #pragma unroll
  for (int i = 0; i < 2; ++i)
    #pragma unroll
    for (int j = 0; j < 4; ++j)
      #pragma unroll
      for (int r = 0; r < 4; ++r) {
        const int row = m0 + wm * 32 + i * 16 + quad * 4 + r;
        const int col = n0 + wn * 64 + j * 16 + cn;
        O[(size_t)row * DM + col] = acc[i][j][r];
      }
}

// Flash sliding-window attention, barrier-free (per-wave LDS only).
// grid (L/64, H), 256 threads; wave = 16 queries; 64-key steps.
#define PSTR 80
__global__ __launch_bounds__(256) void attn_fwd(
    const unsigned short* __restrict__ Q,
    const unsigned short* __restrict__ K,
    const unsigned short* __restrict__ Vt,
    unsigned short* __restrict__ Oa)
{
  __shared__ unsigned short Pl[4][16 * PSTR];
  const int h    = blockIdx.y;
  const int bq0  = blockIdx.x * 64;
  const int wave = threadIdx.x >> 6;
  const int lane = threadIdx.x & 63;
  const int n = lane & 15, quad = lane >> 4;
  const int q0 = bq0 + wave * 16;
  unsigned short* pl = Pl[wave];
  const float scl = 0.125f * 1.44269504f;   // 1/sqrt(64) * log2(e)

  const size_t qbase = ((size_t)(h * LSEQ + q0 + n)) * DH + quad * 8;
  const bf16x8 aq0 = *(const bf16x8*)(Q + qbase);
  const bf16x8 aq1 = *(const bf16x8*)(Q + qbase + 32);

  const f32x4 zero = {0.f, 0.f, 0.f, 0.f};
  f32x4 acc[4] = {zero, zero, zero, zero};
  float mi[4], li[4];
  #pragma unroll
  for (int r = 0; r < 4; ++r) { mi[r] = -1e28f; li[r] = 0.f; }

  const int jb0 = (bq0 >= WIN) ? (bq0 - WIN) : 0;
  for (int jb = jb0; jb < bq0 + 64; jb += 64) {
    f32x4 s[4];
    #pragma unroll
    for (int u = 0; u < 4; ++u) {
      const int j0 = jb + u * 16;
      const size_t kbase = ((size_t)(h * LSEQ + j0 + n)) * DH + quad * 8;
      const bf16x8 kb0 = *(const bf16x8*)(K + kbase);
      const bf16x8 kb1 = *(const bf16x8*)(K + kbase + 32);
      f32x4 c = zero;
      c = __builtin_amdgcn_mfma_f32_16x16x32_bf16(aq0, kb0, c, 0, 0, 0);
      c = __builtin_amdgcn_mfma_f32_16x16x32_bf16(aq1, kb1, c, 0, 0, 0);
      #pragma unroll
      for (int r = 0; r < 4; ++r) {
        const int qi = q0 + quad * 4 + r;
        const int kj = j0 + n;
        const bool ok = (kj <= qi) && (kj + WIN > qi);
        s[u][r] = ok ? c[r] * scl : -1e30f;
      }
    }
    float alpha[4];
    #pragma unroll
    for (int r = 0; r < 4; ++r) {
      float v = fmaxf(fmaxf(s[0][r], s[1][r]), fmaxf(s[2][r], s[3][r]));
      v = fmaxf(v, __shfl_xor(v, 1));
      v = fmaxf(v, __shfl_xor(v, 2));
      v = fmaxf(v, __shfl_xor(v, 4));
      v = fmaxf(v, __shfl_xor(v, 8));
      const float mn = fmaxf(mi[r], v);
      alpha[r] = __builtin_exp2f(mi[r] - mn);
      mi[r] = mn;
    }
    #pragma unroll
    for (int u = 0; u < 4; ++u)
      #pragma unroll
      for (int r = 0; r < 4; ++r)
        s[u][r] = __builtin_exp2f(s[u][r] - mi[r]);
    #pragma unroll
    for (int r = 0; r < 4; ++r) {
      float v = (s[0][r] + s[1][r]) + (s[2][r] + s[3][r]);
      v += __shfl_xor(v, 1);
      v += __shfl_xor(v, 2);
      v += __shfl_xor(v, 4);
      v += __shfl_xor(v, 8);
      li[r] = li[r] * alpha[r] + v;
      acc[0][r] *= alpha[r];
      acc[1][r] *= alpha[r];
      acc[2][r] *= alpha[r];
      acc[3][r] *= alpha[r];
    }
    #pragma unroll
    for (int u = 0; u < 4; ++u)
      #pragma unroll
      for (int r = 0; r < 4; ++r)
        pl[(quad * 4 + r) * PSTR + u * 16 + n] = f2bf(s[u][r]);
    asm volatile("s_waitcnt lgkmcnt(0)" ::: "memory");
    const bf16x8 pa0 = *(const bf16x8*)(pl + n * PSTR + quad * 8);
    const bf16x8 pa1 = *(const bf16x8*)(pl + n * PSTR + 32 + quad * 8);
    #pragma unroll
    for (int ct = 0; ct < 4; ++ct) {
      const size_t vb = ((size_t)(h * DH + ct * 16 + n)) * LSEQ + jb + quad * 8;
      const bf16x8 vb0 = *(const bf16x8*)(Vt + vb);
      const bf16x8 vb1 = *(const bf16x8*)(Vt + vb + 32);
      acc[ct] = __builtin_amdgcn_mfma_f32_16x16x32_bf16(pa0, vb0, acc[ct], 0, 0, 0);
      acc[ct] = __builtin_amdgcn_mfma_f32_16x16x32_bf16(pa1, vb1, acc[ct], 0, 0, 0);
    }
  }

  #pragma unroll
  for (int ct = 0; ct < 4; ++ct)
    #pragma unroll
    for (int r = 0; r < 4; ++r) {
      const int row = q0 + quad * 4 + r;
      const int col = h * DH + ct * 16 + n;
      Oa[(size_t)row * DM + col] = f2bf(acc[ct][r] / li[r]);
    }
}

extern "C" void kernel_launch(void* const* d_in, const int* in_sizes, int n_in,
                              void* d_out, int out_size, void* d_ws, size_t ws_size,
                              hipStream_t stream) {
  const float* x  = (const float*)d_in[0];
  const float* Wq = (const float*)d_in[1];
  const float* Wk = (const float*)d_in[2];
  const float* Wv = (const float*)d_in[3];
  const float* Wo = (const float*)d_in[4];
  float* out = (float*)d_out;               // fp32 output (proven R6)

  unsigned short* xb  = (unsigned short*)d_ws;            // [L][DM]    8 MiB
  unsigned short* Wqb = xb  + (size_t)LSEQ * DM;          // 2 MiB each
  unsigned short* Wkb = Wqb + (size_t)DM * DM;
  unsigned short* Wvb = Wkb + (size_t)DM * DM;
  unsigned short* Wob = Wvb + (size_t)DM * DM;
  unsigned short* Q    = Wob + (size_t)DM * DM;           // [H][L][64] 8 MiB
  unsigned short* K    = Q   + (size_t)LSEQ * DM;
  unsigned short* Vt   = K   + (size_t)LSEQ * DM;         // [H*DH][L]
  unsigned short* Attn = Vt  + (size_t)LSEQ * DM;         // [L][DM]
  // total 48 MiB (ws >= 64 MiB, proven R4)

  cvt5<<<dim3(2048, 5), 256, 0, stream>>>(x, Wq, Wk, Wv, Wo, xb, Wqb, Wkb, Wvb, Wob);
  qk_gemm<<<dim3(32, 16), 256, 0, stream>>>(xb, Wqb, Wkb, Q, K);
  v_gemm_t<<<dim3(8, 32), 256, 0, stream>>>(xb, Wvb, Vt);
  attn_fwd<<<dim3(64, 16), 256, 0, stream>>>(Q, K, Vt, Attn);
  out_gemm<<<dim3(64, 8), 256, 0, stream>>>(Attn, Wob, out);
}

// Round 10
// 175.675 us; speedup vs baseline: 9.7226x; 1.0906x over previous
//
#include <hip/hip_runtime.h>

using bf16x8 = __attribute__((ext_vector_type(8))) short;
using u16x8  = __attribute__((ext_vector_type(8))) unsigned short;
using f32x4  = __attribute__((ext_vector_type(4))) float;

#define LSEQ   4096
#define NH     16
#define DH     64
#define WIN    256
#define DM     1024

// async global->LDS, 16B per lane; LDS dest is wave-uniform base + lane*16
__device__ __forceinline__ void gl2lds16(const void* g, void* l) {
  __builtin_amdgcn_global_load_lds(
      (const __attribute__((address_space(1))) unsigned int*)g,
      (__attribute__((address_space(3))) unsigned int*)l,
      16, 0, 0);
}

// fp32 -> bf16 RNE (finite inputs only)
__device__ __forceinline__ unsigned short f2bf(float f) {
  unsigned int u = __float_as_uint(f);
  u += 0x7fffu + ((u >> 16) & 1u);
  return (unsigned short)(u >> 16);
}

// ---- fp32 -> bf16, exact-size flat kernel over the contiguous ws image ----
// dst layout: xb(4M) | Wqb(1M) | Wkb(1M) | Wvb(1M) | Wob(1M)  = 8M elems
__global__ __launch_bounds__(256) void cvt_all(
    const float* __restrict__ x,  const float* __restrict__ wq,
    const float* __restrict__ wk, const float* __restrict__ wv,
    const float* __restrict__ wo, unsigned short* __restrict__ dst)
{
  const size_t i = ((size_t)blockIdx.x * 256 + threadIdx.x) * 8;
  const size_t XN = (size_t)LSEQ * DM;          // 4M
  const float* src;
  size_t off;
  if (i < XN) { src = x; off = i; }
  else {
    const size_t j = i - XN;
    const int s = (int)(j >> 20);                // 1M elems per weight
    off = j & ((1u << 20) - 1);
    src = (s == 0) ? wq : (s == 1) ? wk : (s == 2) ? wv : wo;
  }
  const f32x4 f0 = *(const f32x4*)(src + off);
  const f32x4 f1 = *(const f32x4*)(src + off + 4);
  u16x8 o;
  o[0] = f2bf(f0[0]); o[1] = f2bf(f0[1]); o[2] = f2bf(f0[2]); o[3] = f2bf(f0[3]);
  o[4] = f2bf(f1[0]); o[5] = f2bf(f1[1]); o[6] = f2bf(f1[2]); o[7] = f2bf(f1[3]);
  *(u16x8*)(dst + i) = o;
}

// 128x128 NT GEMM tile (validated R2==R4): global_load_lds + 16x16x32 MFMA
__device__ __forceinline__ void gemm_tile(
    const unsigned short* __restrict__ X,
    const unsigned short* __restrict__ W,
    int m0, int n0,
    unsigned short* As, unsigned short* Bs,
    f32x4 (&acc)[4][4])
{
  const int tid  = threadIdx.x;
  const int lane = tid & 63;
  const int wave = tid >> 6;
  const int wm = wave >> 1, wn = wave & 1;
  const int fr = lane & 15, quad = lane >> 4;

  const f32x4 zero = {0.f, 0.f, 0.f, 0.f};
  #pragma unroll
  for (int i = 0; i < 4; ++i)
    #pragma unroll
    for (int j = 0; j < 4; ++j)
      acc[i][j] = zero;

  const int c0 = tid, c1 = tid + 256;
  const unsigned short* xa0 = X + (size_t)(m0 + (c0 >> 2)) * DM + (c0 & 3) * 8;
  const unsigned short* xa1 = X + (size_t)(m0 + (c1 >> 2)) * DM + (c1 & 3) * 8;
  const unsigned short* wb0 = W + (size_t)(n0 + (c0 >> 2)) * DM + (c0 & 3) * 8;
  const unsigned short* wb1 = W + (size_t)(n0 + (c1 >> 2)) * DM + (c1 & 3) * 8;
  char* la0 = (char*)As + c0 * 16;
  char* la1 = (char*)As + c1 * 16;
  char* lb0 = (char*)Bs + c0 * 16;
  char* lb1 = (char*)Bs + c1 * 16;

  for (int kt = 0; kt < DM; kt += 32) {
    gl2lds16(xa0 + kt, la0);
    gl2lds16(xa1 + kt, la1);
    gl2lds16(wb0 + kt, lb0);
    gl2lds16(wb1 + kt, lb1);
    __syncthreads();

    bf16x8 a[4], b[4];
    #pragma unroll
    for (int t = 0; t < 4; ++t)
      a[t] = *(const bf16x8*)(As + (wm * 64 + t * 16 + fr) * 32 + quad * 8);
    #pragma unroll
    for (int t = 0; t < 4; ++t)
      b[t] = *(const bf16x8*)(Bs + (wn * 64 + t * 16 + fr) * 32 + quad * 8);

    #pragma unroll
    for (int i = 0; i < 4; ++i)
      #pragma unroll
      for (int j = 0; j < 4; ++j)
        acc[i][j] = __builtin_amdgcn_mfma_f32_16x16x32_bf16(a[i], b[j], acc[i][j], 0, 0, 0);
    __syncthreads();
  }
}

// Merged projections, grid (768):
//  id < 512: Q/K  (id&31 = m-block, id>>5: wsel = >>3, col-block = &7)
//            Q is pre-scaled by 0.125*log2(e) (folded softmax scale)
//  id >= 512: V^T by operand swap (C-layout col = token -> coalesced stores)
__global__ __launch_bounds__(256) void proj_gemm(
    const unsigned short* __restrict__ X,
    const unsigned short* __restrict__ Wq,
    const unsigned short* __restrict__ Wk,
    const unsigned short* __restrict__ Wv,
    unsigned short* __restrict__ Qo,
    unsigned short* __restrict__ Ko,
    unsigned short* __restrict__ Vt)
{
  __shared__ unsigned short As[128 * 32];
  __shared__ unsigned short Bs[128 * 32];
  const int id = blockIdx.x;
  const int lane = threadIdx.x & 63;
  const int wave = threadIdx.x >> 6;
  const int wm = wave >> 1, wn = wave & 1;
  const int cn = lane & 15, quad = lane >> 4;
  f32x4 acc[4][4];

  if (id < 512) {
    const int m0   = (id & 31) * 128;
    const int by   = id >> 5;
    const int wsel = by >> 3;
    const int n0   = (by & 7) * 128;
    gemm_tile(X, wsel ? Wk : Wq, m0, n0, As, Bs, acc);

    const float qscl = wsel ? 1.0f : 0.180336881f;   // 0.125 * log2(e)
    unsigned short* O = wsel ? Ko : Qo;
    #pragma unroll
    for (int i = 0; i < 4; ++i)
      #pragma unroll
      for (int j = 0; j < 4; ++j)
        #pragma unroll
        for (int r = 0; r < 4; ++r) {
          const int row = m0 + wm * 64 + i * 16 + quad * 4 + r;
          const int col = n0 + wn * 64 + j * 16 + cn;
          const int h = col >> 6, d = col & 63;
          O[(size_t)(h * LSEQ + row) * DH + d] = f2bf(acc[i][j][r] * qscl);
        }
  } else {
    const int vid = id - 512;
    const int m0 = (vid & 7) * 128;    // d-block (H*DH)
    const int n0 = (vid >> 3) * 128;   // token-block
    gemm_tile(Wv, X, m0, n0, As, Bs, acc);

    #pragma unroll
    for (int i = 0; i < 4; ++i)
      #pragma unroll
      for (int j = 0; j < 4; ++j)
        #pragma unroll
        for (int r = 0; r < 4; ++r) {
          const int row = m0 + wm * 64 + i * 16 + quad * 4 + r;   // d
          const int col = n0 + wn * 64 + j * 16 + cn;             // token
          Vt[(size_t)row * LSEQ + col] = f2bf(acc[i][j][r]);
        }
  }
}

// Output projection, 64x128 tiles: grid (64, 8), fp32 store
__global__ __launch_bounds__(256) void out_gemm(
    const unsigned short* __restrict__ X,
    const unsigned short* __restrict__ W,
    float* __restrict__ O)
{
  __shared__ unsigned short As2[64 * 32];
  __shared__ unsigned short Bs[128 * 32];
  const int m0 = blockIdx.x * 64;
  const int n0 = blockIdx.y * 128;
  const int tid  = threadIdx.x;
  const int lane = tid & 63;
  const int wave = tid >> 6;
  const int wm = wave >> 1, wn = wave & 1;
  const int fr = lane & 15, quad = lane >> 4;

  const f32x4 zero = {0.f, 0.f, 0.f, 0.f};
  f32x4 acc[2][4];
  #pragma unroll
  for (int i = 0; i < 2; ++i)
    #pragma unroll
    for (int j = 0; j < 4; ++j)
      acc[i][j] = zero;

  const unsigned short* xa  = X + (size_t)(m0 + (tid >> 2)) * DM + (tid & 3) * 8;
  const unsigned short* wb0 = W + (size_t)(n0 + (tid >> 2)) * DM + (tid & 3) * 8;
  const unsigned short* wb1 = W + (size_t)(n0 + ((tid + 256) >> 2)) * DM + (tid & 3) * 8;
  char* la  = (char*)As2 + tid * 16;
  char* lb0 = (char*)Bs + tid * 16;
  char* lb1 = (char*)Bs + (tid + 256) * 16;

  for (int kt = 0; kt < DM; kt += 32) {
    gl2lds16(xa + kt, la);
    gl2lds16(wb0 + kt, lb0);
    gl2lds16(wb1 + kt, lb1);
    __syncthreads();

    bf16x8 a[2], b[4];
    #pragma unroll
    for (int t = 0; t < 2; ++t)
      a[t] = *(const bf16x8*)(As2 + (wm * 32 + t * 16 + fr) * 32 + quad * 8);
    #pragma unroll
    for (int t = 0; t < 4; ++t)
      b[t] = *(const bf16x8*)(Bs + (wn * 64 + t * 16 + fr) * 32 + quad * 8);

    #pragma unroll
    for (int i = 0; i < 2; ++i)
      #pragma unroll
      for (int j = 0; j < 4; ++j)
        acc[i][j] = __builtin_amdgcn_mfma_f32_16x16x32_bf16(a[i], b[j], acc[i][j], 0, 0, 0);
    __syncthreads();
  }

  const int cn = lane & 15;
  #pragma unroll
  for (int i = 0; i < 2; ++i)
    #pragma unroll
    for (int j = 0; j < 4; ++j)
      #pragma unroll
      for (int r = 0; r < 4; ++r) {
        const int row = m0 + wm * 32 + i * 16 + quad * 4 + r;
        const int col = n0 + wn * 64 + j * 16 + cn;
        O[(size_t)row * DM + col] = acc[i][j][r];
      }
}

// Flash sliding-window attention, fixed-shift softmax (shift-invariant:
// exact same math as max-shift; M=32 guarantees no overflow for |s|<160
// and l>0 via the causal diagonal s_qq = |q|^2*scl > 0).
// Q comes in pre-scaled by 0.125*log2(e); exp2-based softmax.
// grid (L/64, H), 256 threads; wave = 16 queries; 64-key steps; barrier-free.
#define PSTR 80
__global__ __launch_bounds__(256) void attn_fwd(
    const unsigned short* __restrict__ Q,
    const unsigned short* __restrict__ K,
    const unsigned short* __restrict__ Vt,
    unsigned short* __restrict__ Oa)
{
  __shared__ unsigned short Pl[4][16 * PSTR];
  const int h    = blockIdx.y;
  const int bq0  = blockIdx.x * 64;
  const int wave = threadIdx.x >> 6;
  const int lane = threadIdx.x & 63;
  const int n = lane & 15, quad = lane >> 4;
  const int q0 = bq0 + wave * 16;
  unsigned short* pl = Pl[wave];

  const size_t qbase = ((size_t)(h * LSEQ + q0 + n)) * DH + quad * 8;
  const bf16x8 aq0 = *(const bf16x8*)(Q + qbase);
  const bf16x8 aq1 = *(const bf16x8*)(Q + qbase + 32);

  const f32x4 zero = {0.f, 0.f, 0.f, 0.f};
  f32x4 acc[4] = {zero, zero, zero, zero};
  float li[4] = {0.f, 0.f, 0.f, 0.f};       // per-lane partial denominators

  const int jb0 = (bq0 >= WIN) ? (bq0 - WIN) : 0;
  for (int jb = jb0; jb < bq0 + 64; jb += 64) {
    // ---- scores for 4 x 16-key subtiles (64 keys), Q pre-scaled
    f32x4 s[4];
    #pragma unroll
    for (int u = 0; u < 4; ++u) {
      const int j0 = jb + u * 16;
      const size_t kbase = ((size_t)(h * LSEQ + j0 + n)) * DH + quad * 8;
      const bf16x8 kb0 = *(const bf16x8*)(K + kbase);
      const bf16x8 kb1 = *(const bf16x8*)(K + kbase + 32);
      f32x4 c = zero;
      c = __builtin_amdgcn_mfma_f32_16x16x32_bf16(aq0, kb0, c, 0, 0, 0);
      c = __builtin_amdgcn_mfma_f32_16x16x32_bf16(aq1, kb1, c, 0, 0, 0);
      s[u] = c;
    }
    // ---- fixed-shift exp2 + per-lane partial sum (no cross-lane per iter)
    #pragma unroll
    for (int u = 0; u < 4; ++u)
      #pragma unroll
      for (int r = 0; r < 4; ++r) {
        const int qi = q0 + quad * 4 + r;
        const int kj = jb + u * 16 + n;
        const bool ok = (kj <= qi) && (kj + WIN > qi);
        const float e = __builtin_exp2f(ok ? s[u][r] - 32.0f : -1e30f);
        s[u][r] = e;
        li[r] += e;
      }
    // ---- P: C-layout regs -> per-wave LDS -> A-operand layout (no barrier)
    #pragma unroll
    for (int u = 0; u < 4; ++u)
      #pragma unroll
      for (int r = 0; r < 4; ++r)
        pl[(quad * 4 + r) * PSTR + u * 16 + n] = f2bf(s[u][r]);
    asm volatile("s_waitcnt lgkmcnt(0)" ::: "memory");
    const bf16x8 pa0 = *(const bf16x8*)(pl + n * PSTR + quad * 8);
    const bf16x8 pa1 = *(const bf16x8*)(pl + n * PSTR + 32 + quad * 8);
    // ---- PV: B-operand from V^T [H*DH][L]
    #pragma unroll
    for (int ct = 0; ct < 4; ++ct) {
      const size_t vb = ((size_t)(h * DH + ct * 16 + n)) * LSEQ + jb + quad * 8;
      const bf16x8 vb0 = *(const bf16x8*)(Vt + vb);
      const bf16x8 vb1 = *(const bf16x8*)(Vt + vb + 32);
      acc[ct] = __builtin_amdgcn_mfma_f32_16x16x32_bf16(pa0, vb0, acc[ct], 0, 0, 0);
      acc[ct] = __builtin_amdgcn_mfma_f32_16x16x32_bf16(pa1, vb1, acc[ct], 0, 0, 0);
    }
  }

  // ---- single cross-lane denominator reduction (16 lanes per quad-row)
  float rd[4];
  #pragma unroll
  for (int r = 0; r < 4; ++r) {
    float v = li[r];
    v += __shfl_xor(v, 1);
    v += __shfl_xor(v, 2);
    v += __shfl_xor(v, 4);
    v += __shfl_xor(v, 8);
    rd[r] = 1.0f / v;
  }
  #pragma unroll
  for (int ct = 0; ct < 4; ++ct)
    #pragma unroll
    for (int r = 0; r < 4; ++r) {
      const int row = q0 + quad * 4 + r;
      const int col = h * DH + ct * 16 + n;
      Oa[(size_t)row * DM + col] = f2bf(acc[ct][r] * rd[r]);
    }
}

extern "C" void kernel_launch(void* const* d_in, const int* in_sizes, int n_in,
                              void* d_out, int out_size, void* d_ws, size_t ws_size,
                              hipStream_t stream) {
  const float* x  = (const float*)d_in[0];
  const float* Wq = (const float*)d_in[1];
  const float* Wk = (const float*)d_in[2];
  const float* Wv = (const float*)d_in[3];
  const float* Wo = (const float*)d_in[4];
  float* out = (float*)d_out;               // fp32 output (proven R6)

  unsigned short* xb  = (unsigned short*)d_ws;            // [L][DM]    8 MiB
  unsigned short* Wqb = xb  + (size_t)LSEQ * DM;          // 2 MiB each
  unsigned short* Wkb = Wqb + (size_t)DM * DM;
  unsigned short* Wvb = Wkb + (size_t)DM * DM;
  unsigned short* Wob = Wvb + (size_t)DM * DM;
  unsigned short* Q    = Wob + (size_t)DM * DM;           // [H][L][64] 8 MiB (pre-scaled)
  unsigned short* K    = Q   + (size_t)LSEQ * DM;
  unsigned short* Vt   = K   + (size_t)LSEQ * DM;         // [H*DH][L]
  unsigned short* Attn = Vt  + (size_t)LSEQ * DM;         // [L][DM]
  // total 48 MiB (ws >= 64 MiB, proven R4)

  cvt_all<<<dim3(4096), 256, 0, stream>>>(x, Wq, Wk, Wv, Wo, xb);
  proj_gemm<<<dim3(768), 256, 0, stream>>>(xb, Wqb, Wkb, Wvb, Q, K, Vt);
  attn_fwd<<<dim3(64, 16), 256, 0, stream>>>(Q, K, Vt, Attn);
  out_gemm<<<dim3(64, 8), 256, 0, stream>>>(Attn, Wob, out);
}

// Round 11
// 174.211 us; speedup vs baseline: 9.8043x; 1.0084x over previous
//
#include <hip/hip_runtime.h>

using bf16x8 = __attribute__((ext_vector_type(8))) short;
using u16x8  = __attribute__((ext_vector_type(8))) unsigned short;
using f32x4  = __attribute__((ext_vector_type(4))) float;

#define LSEQ   4096
#define NH     16
#define DH     64
#define WIN    256
#define DM     1024

// async global->LDS, 16B per lane; LDS dest is wave-uniform base + lane*16
__device__ __forceinline__ void gl2lds16(const void* g, void* l) {
  __builtin_amdgcn_global_load_lds(
      (const __attribute__((address_space(1))) unsigned int*)g,
      (__attribute__((address_space(3))) unsigned int*)l,
      16, 0, 0);
}

// fp32 -> bf16 RNE (finite inputs only)
__device__ __forceinline__ unsigned short f2bf(float f) {
  unsigned int u = __float_as_uint(f);
  u += 0x7fffu + ((u >> 16) & 1u);
  return (unsigned short)(u >> 16);
}

// ---- fp32 -> bf16, exact-size flat kernel over the contiguous ws image ----
__global__ __launch_bounds__(256) void cvt_all(
    const float* __restrict__ x,  const float* __restrict__ wq,
    const float* __restrict__ wk, const float* __restrict__ wv,
    const float* __restrict__ wo, unsigned short* __restrict__ dst)
{
  const size_t i = ((size_t)blockIdx.x * 256 + threadIdx.x) * 8;
  const size_t XN = (size_t)LSEQ * DM;          // 4M
  const float* src;
  size_t off;
  if (i < XN) { src = x; off = i; }
  else {
    const size_t j = i - XN;
    const int s = (int)(j >> 20);                // 1M elems per weight
    off = j & ((1u << 20) - 1);
    src = (s == 0) ? wq : (s == 1) ? wk : (s == 2) ? wv : wo;
  }
  const f32x4 f0 = *(const f32x4*)(src + off);
  const f32x4 f1 = *(const f32x4*)(src + off + 4);
  u16x8 o;
  o[0] = f2bf(f0[0]); o[1] = f2bf(f0[1]); o[2] = f2bf(f0[2]); o[3] = f2bf(f0[3]);
  o[4] = f2bf(f1[0]); o[5] = f2bf(f1[1]); o[6] = f2bf(f1[2]); o[7] = f2bf(f1[3]);
  *(u16x8*)(dst + i) = o;
}

// 128x128 NT GEMM tile (validated R2==R4): global_load_lds + 16x16x32 MFMA
__device__ __forceinline__ void gemm_tile(
    const unsigned short* __restrict__ X,
    const unsigned short* __restrict__ W,
    int m0, int n0,
    unsigned short* As, unsigned short* Bs,
    f32x4 (&acc)[4][4])
{
  const int tid  = threadIdx.x;
  const int lane = tid & 63;
  const int wave = tid >> 6;
  const int wm = wave >> 1, wn = wave & 1;
  const int fr = lane & 15, quad = lane >> 4;

  const f32x4 zero = {0.f, 0.f, 0.f, 0.f};
  #pragma unroll
  for (int i = 0; i < 4; ++i)
    #pragma unroll
    for (int j = 0; j < 4; ++j)
      acc[i][j] = zero;

  const int c0 = tid, c1 = tid + 256;
  const unsigned short* xa0 = X + (size_t)(m0 + (c0 >> 2)) * DM + (c0 & 3) * 8;
  const unsigned short* xa1 = X + (size_t)(m0 + (c1 >> 2)) * DM + (c1 & 3) * 8;
  const unsigned short* wb0 = W + (size_t)(n0 + (c0 >> 2)) * DM + (c0 & 3) * 8;
  const unsigned short* wb1 = W + (size_t)(n0 + (c1 >> 2)) * DM + (c1 & 3) * 8;
  char* la0 = (char*)As + c0 * 16;
  char* la1 = (char*)As + c1 * 16;
  char* lb0 = (char*)Bs + c0 * 16;
  char* lb1 = (char*)Bs + c1 * 16;

  for (int kt = 0; kt < DM; kt += 32) {
    gl2lds16(xa0 + kt, la0);
    gl2lds16(xa1 + kt, la1);
    gl2lds16(wb0 + kt, lb0);
    gl2lds16(wb1 + kt, lb1);
    __syncthreads();

    bf16x8 a[4], b[4];
    #pragma unroll
    for (int t = 0; t < 4; ++t)
      a[t] = *(const bf16x8*)(As + (wm * 64 + t * 16 + fr) * 32 + quad * 8);
    #pragma unroll
    for (int t = 0; t < 4; ++t)
      b[t] = *(const bf16x8*)(Bs + (wn * 64 + t * 16 + fr) * 32 + quad * 8);

    #pragma unroll
    for (int i = 0; i < 4; ++i)
      #pragma unroll
      for (int j = 0; j < 4; ++j)
        acc[i][j] = __builtin_amdgcn_mfma_f32_16x16x32_bf16(a[i], b[j], acc[i][j], 0, 0, 0);
    __syncthreads();
  }
}

// Merged projections, grid (768): id<512 Q/K; id>=512 V^T (operand swap)
__global__ __launch_bounds__(256) void proj_gemm(
    const unsigned short* __restrict__ X,
    const unsigned short* __restrict__ Wq,
    const unsigned short* __restrict__ Wk,
    const unsigned short* __restrict__ Wv,
    unsigned short* __restrict__ Qo,
    unsigned short* __restrict__ Ko,
    unsigned short* __restrict__ Vt)
{
  __shared__ unsigned short As[128 * 32];
  __shared__ unsigned short Bs[128 * 32];
  const int id = blockIdx.x;
  const int lane = threadIdx.x & 63;
  const int wave = threadIdx.x >> 6;
  const int wm = wave >> 1, wn = wave & 1;
  const int cn = lane & 15, quad = lane >> 4;
  f32x4 acc[4][4];

  if (id < 512) {
    const int m0   = (id & 31) * 128;
    const int by   = id >> 5;
    const int wsel = by >> 3;
    const int n0   = (by & 7) * 128;
    gemm_tile(X, wsel ? Wk : Wq, m0, n0, As, Bs, acc);

    const float qscl = wsel ? 1.0f : 0.180336881f;   // 0.125 * log2(e)
    unsigned short* O = wsel ? Ko : Qo;
    #pragma unroll
    for (int i = 0; i < 4; ++i)
      #pragma unroll
      for (int j = 0; j < 4; ++j)
        #pragma unroll
        for (int r = 0; r < 4; ++r) {
          const int row = m0 + wm * 64 + i * 16 + quad * 4 + r;
          const int col = n0 + wn * 64 + j * 16 + cn;
          const int h = col >> 6, d = col & 63;
          O[(size_t)(h * LSEQ + row) * DH + d] = f2bf(acc[i][j][r] * qscl);
        }
  } else {
    const int vid = id - 512;
    const int m0 = (vid & 7) * 128;    // d-block (H*DH)
    const int n0 = (vid >> 3) * 128;   // token-block
    gemm_tile(Wv, X, m0, n0, As, Bs, acc);

    #pragma unroll
    for (int i = 0; i < 4; ++i)
      #pragma unroll
      for (int j = 0; j < 4; ++j)
        #pragma unroll
        for (int r = 0; r < 4; ++r) {
          const int row = m0 + wm * 64 + i * 16 + quad * 4 + r;   // d
          const int col = n0 + wn * 64 + j * 16 + cn;             // token
          Vt[(size_t)row * LSEQ + col] = f2bf(acc[i][j][r]);
        }
  }
}

// Output projection, 64x128 tiles: grid (64, 8), fp32 store
__global__ __launch_bounds__(256) void out_gemm(
    const unsigned short* __restrict__ X,
    const unsigned short* __restrict__ W,
    float* __restrict__ O)
{
  __shared__ unsigned short As2[64 * 32];
  __shared__ unsigned short Bs[128 * 32];
  const int m0 = blockIdx.x * 64;
  const int n0 = blockIdx.y * 128;
  const int tid  = threadIdx.x;
  const int lane = tid & 63;
  const int wave = tid >> 6;
  const int wm = wave >> 1, wn = wave & 1;
  const int fr = lane & 15, quad = lane >> 4;

  const f32x4 zero = {0.f, 0.f, 0.f, 0.f};
  f32x4 acc[2][4];
  #pragma unroll
  for (int i = 0; i < 2; ++i)
    #pragma unroll
    for (int j = 0; j < 4; ++j)
      acc[i][j] = zero;

  const unsigned short* xa  = X + (size_t)(m0 + (tid >> 2)) * DM + (tid & 3) * 8;
  const unsigned short* wb0 = W + (size_t)(n0 + (tid >> 2)) * DM + (tid & 3) * 8;
  const unsigned short* wb1 = W + (size_t)(n0 + ((tid + 256) >> 2)) * DM + (tid & 3) * 8;
  char* la  = (char*)As2 + tid * 16;
  char* lb0 = (char*)Bs + tid * 16;
  char* lb1 = (char*)Bs + (tid + 256) * 16;

  for (int kt = 0; kt < DM; kt += 32) {
    gl2lds16(xa + kt, la);
    gl2lds16(wb0 + kt, lb0);
    gl2lds16(wb1 + kt, lb1);
    __syncthreads();

    bf16x8 a[2], b[4];
    #pragma unroll
    for (int t = 0; t < 2; ++t)
      a[t] = *(const bf16x8*)(As2 + (wm * 32 + t * 16 + fr) * 32 + quad * 8);
    #pragma unroll
    for (int t = 0; t < 4; ++t)
      b[t] = *(const bf16x8*)(Bs + (wn * 64 + t * 16 + fr) * 32 + quad * 8);

    #pragma unroll
    for (int i = 0; i < 2; ++i)
      #pragma unroll
      for (int j = 0; j < 4; ++j)
        acc[i][j] = __builtin_amdgcn_mfma_f32_16x16x32_bf16(a[i], b[j], acc[i][j], 0, 0, 0);
    __syncthreads();
  }

  const int cn = lane & 15;
  #pragma unroll
  for (int i = 0; i < 2; ++i)
    #pragma unroll
    for (int j = 0; j < 4; ++j)
      #pragma unroll
      for (int r = 0; r < 4; ++r) {
        const int row = m0 + wm * 32 + i * 16 + quad * 4 + r;
        const int col = n0 + wn * 64 + j * 16 + cn;
        O[(size_t)row * DM + col] = acc[i][j][r];
      }
}

// Flash sliding-window attention, fixed-shift exp2 softmax.
// R11: all K+V loads batch-issued per iteration (1 vmcnt wait, not 8);
// XCD-swizzled block id for K/V L2 locality; PSTR=72 (2-way LDS, was 8-way).
// grid flat (1024): id = 8*qtile + (h&7) + 512*(h>>3)  -> same-XCD blocks
// (stride 8) are q-adjacent with overlapping K windows.
#define PSTR 72
__global__ __launch_bounds__(256) void attn_fwd(
    const unsigned short* __restrict__ Q,
    const unsigned short* __restrict__ K,
    const unsigned short* __restrict__ Vt,
    unsigned short* __restrict__ Oa)
{
  __shared__ unsigned short Pl[4][16 * PSTR];
  const int id   = blockIdx.x;
  const int h    = (id & 7) | ((id >> 9) << 3);
  const int bq0  = ((id >> 3) & 63) * 64;
  const int wave = threadIdx.x >> 6;
  const int lane = threadIdx.x & 63;
  const int n = lane & 15, quad = lane >> 4;
  const int q0 = bq0 + wave * 16;
  unsigned short* pl = Pl[wave];

  const size_t qbase = ((size_t)(h * LSEQ + q0 + n)) * DH + quad * 8;
  const bf16x8 aq0 = *(const bf16x8*)(Q + qbase);   // Q pre-scaled by 0.125*log2e
  const bf16x8 aq1 = *(const bf16x8*)(Q + qbase + 32);

  const f32x4 zero = {0.f, 0.f, 0.f, 0.f};
  f32x4 acc[4] = {zero, zero, zero, zero};
  float li[4] = {0.f, 0.f, 0.f, 0.f};       // per-lane partial denominators

  const int jb0 = (bq0 >= WIN) ? (bq0 - WIN) : 0;
  for (int jb = jb0; jb < bq0 + 64; jb += 64) {
    // ---- batch-issue ALL memory for this iteration (16 x dwordx4) --------
    bf16x8 kb[4][2], vv[4][2];
    #pragma unroll
    for (int u = 0; u < 4; ++u) {
      const size_t kbase = ((size_t)(h * LSEQ + jb + u * 16 + n)) * DH + quad * 8;
      kb[u][0] = *(const bf16x8*)(K + kbase);
      kb[u][1] = *(const bf16x8*)(K + kbase + 32);
    }
    #pragma unroll
    for (int ct = 0; ct < 4; ++ct) {
      const size_t vbase = ((size_t)(h * DH + ct * 16 + n)) * LSEQ + jb + quad * 8;
      vv[ct][0] = *(const bf16x8*)(Vt + vbase);
      vv[ct][1] = *(const bf16x8*)(Vt + vbase + 32);
    }
    // ---- QK scores (K regs ready after one vmcnt wait; V still in flight)
    f32x4 s[4];
    #pragma unroll
    for (int u = 0; u < 4; ++u) {
      f32x4 c = zero;
      c = __builtin_amdgcn_mfma_f32_16x16x32_bf16(aq0, kb[u][0], c, 0, 0, 0);
      c = __builtin_amdgcn_mfma_f32_16x16x32_bf16(aq1, kb[u][1], c, 0, 0, 0);
      s[u] = c;
    }
    // ---- fixed-shift exp2 + per-lane partial denominator
    #pragma unroll
    for (int u = 0; u < 4; ++u)
      #pragma unroll
      for (int r = 0; r < 4; ++r) {
        const int qi = q0 + quad * 4 + r;
        const int kj = jb + u * 16 + n;
        const bool ok = (kj <= qi) && (kj + WIN > qi);
        const float e = __builtin_exp2f(ok ? s[u][r] - 32.0f : -1e30f);
        s[u][r] = e;
        li[r] += e;
      }
    // ---- P: C-layout regs -> per-wave LDS -> A-operand layout
    #pragma unroll
    for (int u = 0; u < 4; ++u)
      #pragma unroll
      for (int r = 0; r < 4; ++r)
        pl[(quad * 4 + r) * PSTR + u * 16 + n] = f2bf(s[u][r]);
    asm volatile("s_waitcnt lgkmcnt(0)" ::: "memory");   // wave-private LDS fence
    const bf16x8 pa0 = *(const bf16x8*)(pl + n * PSTR + quad * 8);
    const bf16x8 pa1 = *(const bf16x8*)(pl + n * PSTR + 32 + quad * 8);
    // ---- PV (V already in registers -- no memory wait here)
    #pragma unroll
    for (int ct = 0; ct < 4; ++ct) {
      acc[ct] = __builtin_amdgcn_mfma_f32_16x16x32_bf16(pa0, vv[ct][0], acc[ct], 0, 0, 0);
      acc[ct] = __builtin_amdgcn_mfma_f32_16x16x32_bf16(pa1, vv[ct][1], acc[ct], 0, 0, 0);
    }
  }

  // ---- single cross-lane denominator reduction
  float rd[4];
  #pragma unroll
  for (int r = 0; r < 4; ++r) {
    float v = li[r];
    v += __shfl_xor(v, 1);
    v += __shfl_xor(v, 2);
    v += __shfl_xor(v, 4);
    v += __shfl_xor(v, 8);
    rd[r] = 1.0f / v;
  }
  #pragma unroll
  for (int ct = 0; ct < 4; ++ct)
    #pragma unroll
    for (int r = 0; r < 4; ++r) {
      const int row = q0 + quad * 4 + r;
      const int col = h * DH + ct * 16 + n;
      Oa[(size_t)row * DM + col] = f2bf(acc[ct][r] * rd[r]);
    }
}

extern "C" void kernel_launch(void* const* d_in, const int* in_sizes, int n_in,
                              void* d_out, int out_size, void* d_ws, size_t ws_size,
                              hipStream_t stream) {
  const float* x  = (const float*)d_in[0];
  const float* Wq = (const float*)d_in[1];
  const float* Wk = (const float*)d_in[2];
  const float* Wv = (const float*)d_in[3];
  const float* Wo = (const float*)d_in[4];
  float* out = (float*)d_out;               // fp32 output (proven R6)

  unsigned short* xb  = (unsigned short*)d_ws;            // [L][DM]    8 MiB
  unsigned short* Wqb = xb  + (size_t)LSEQ * DM;          // 2 MiB each
  unsigned short* Wkb = Wqb + (size_t)DM * DM;
  unsigned short* Wvb = Wkb + (size_t)DM * DM;
  unsigned short* Wob = Wvb + (size_t)DM * DM;
  unsigned short* Q    = Wob + (size_t)DM * DM;           // [H][L][64] 8 MiB (pre-scaled)
  unsigned short* K    = Q   + (size_t)LSEQ * DM;
  unsigned short* Vt   = K   + (size_t)LSEQ * DM;         // [H*DH][L]
  unsigned short* Attn = Vt  + (size_t)LSEQ * DM;         // [L][DM]
  // total 48 MiB (ws >= 64 MiB, proven R4)

  cvt_all<<<dim3(4096), 256, 0, stream>>>(x, Wq, Wk, Wv, Wo, xb);
  proj_gemm<<<dim3(768), 256, 0, stream>>>(xb, Wqb, Wkb, Wvb, Q, K, Vt);
  attn_fwd<<<dim3(1024), 256, 0, stream>>>(Q, K, Vt, Attn);
  out_gemm<<<dim3(64, 8), 256, 0, stream>>>(Attn, Wob, out);
}

// Round 12
// 174.032 us; speedup vs baseline: 9.8144x; 1.0010x over previous
//
#include <hip/hip_runtime.h>

using bf16x8 = __attribute__((ext_vector_type(8))) short;
using u16x8  = __attribute__((ext_vector_type(8))) unsigned short;
using f32x4  = __attribute__((ext_vector_type(4))) float;

#define LSEQ   4096
#define NH     16
#define DH     64
#define WIN    256
#define DM     1024

// async global->LDS, 16B per lane; LDS dest is wave-uniform base + lane*16
__device__ __forceinline__ void gl2lds16(const void* g, void* l) {
  __builtin_amdgcn_global_load_lds(
      (const __attribute__((address_space(1))) unsigned int*)g,
      (__attribute__((address_space(3))) unsigned int*)l,
      16, 0, 0);
}

// fp32 -> bf16 RNE (finite inputs only)
__device__ __forceinline__ unsigned short f2bf(float f) {
  unsigned int u = __float_as_uint(f);
  u += 0x7fffu + ((u >> 16) & 1u);
  return (unsigned short)(u >> 16);
}

// ---- fp32 -> bf16, exact-size flat kernel over the contiguous ws image ----
__global__ __launch_bounds__(256) void cvt_all(
    const float* __restrict__ x,  const float* __restrict__ wq,
    const float* __restrict__ wk, const float* __restrict__ wv,
    const float* __restrict__ wo, unsigned short* __restrict__ dst)
{
  const size_t i = ((size_t)blockIdx.x * 256 + threadIdx.x) * 8;
  const size_t XN = (size_t)LSEQ * DM;          // 4M
  const float* src;
  size_t off;
  if (i < XN) { src = x; off = i; }
  else {
    const size_t j = i - XN;
    const int s = (int)(j >> 20);                // 1M elems per weight
    off = j & ((1u << 20) - 1);
    src = (s == 0) ? wq : (s == 1) ? wk : (s == 2) ? wv : wo;
  }
  const f32x4 f0 = *(const f32x4*)(src + off);
  const f32x4 f1 = *(const f32x4*)(src + off + 4);
  u16x8 o;
  o[0] = f2bf(f0[0]); o[1] = f2bf(f0[1]); o[2] = f2bf(f0[2]); o[3] = f2bf(f0[3]);
  o[4] = f2bf(f1[0]); o[5] = f2bf(f1[1]); o[6] = f2bf(f1[2]); o[7] = f2bf(f1[3]);
  *(u16x8*)(dst + i) = o;
}

// 128x128 NT GEMM tile (validated R2==R4): global_load_lds + 16x16x32 MFMA
__device__ __forceinline__ void gemm_tile(
    const unsigned short* __restrict__ X,
    const unsigned short* __restrict__ W,
    int m0, int n0,
    unsigned short* As, unsigned short* Bs,
    f32x4 (&acc)[4][4])
{
  const int tid  = threadIdx.x;
  const int lane = tid & 63;
  const int wave = tid >> 6;
  const int wm = wave >> 1, wn = wave & 1;
  const int fr = lane & 15, quad = lane >> 4;

  const f32x4 zero = {0.f, 0.f, 0.f, 0.f};
  #pragma unroll
  for (int i = 0; i < 4; ++i)
    #pragma unroll
    for (int j = 0; j < 4; ++j)
      acc[i][j] = zero;

  const int c0 = tid, c1 = tid + 256;
  const unsigned short* xa0 = X + (size_t)(m0 + (c0 >> 2)) * DM + (c0 & 3) * 8;
  const unsigned short* xa1 = X + (size_t)(m0 + (c1 >> 2)) * DM + (c1 & 3) * 8;
  const unsigned short* wb0 = W + (size_t)(n0 + (c0 >> 2)) * DM + (c0 & 3) * 8;
  const unsigned short* wb1 = W + (size_t)(n0 + (c1 >> 2)) * DM + (c1 & 3) * 8;
  char* la0 = (char*)As + c0 * 16;
  char* la1 = (char*)As + c1 * 16;
  char* lb0 = (char*)Bs + c0 * 16;
  char* lb1 = (char*)Bs + c1 * 16;

  for (int kt = 0; kt < DM; kt += 32) {
    gl2lds16(xa0 + kt, la0);
    gl2lds16(xa1 + kt, la1);
    gl2lds16(wb0 + kt, lb0);
    gl2lds16(wb1 + kt, lb1);
    __syncthreads();

    bf16x8 a[4], b[4];
    #pragma unroll
    for (int t = 0; t < 4; ++t)
      a[t] = *(const bf16x8*)(As + (wm * 64 + t * 16 + fr) * 32 + quad * 8);
    #pragma unroll
    for (int t = 0; t < 4; ++t)
      b[t] = *(const bf16x8*)(Bs + (wn * 64 + t * 16 + fr) * 32 + quad * 8);

    #pragma unroll
    for (int i = 0; i < 4; ++i)
      #pragma unroll
      for (int j = 0; j < 4; ++j)
        acc[i][j] = __builtin_amdgcn_mfma_f32_16x16x32_bf16(a[i], b[j], acc[i][j], 0, 0, 0);
    __syncthreads();
  }
}

// Merged projections, grid (768): id<512 Q/K; id>=512 V^T (operand swap)
__global__ __launch_bounds__(256) void proj_gemm(
    const unsigned short* __restrict__ X,
    const unsigned short* __restrict__ Wq,
    const unsigned short* __restrict__ Wk,
    const unsigned short* __restrict__ Wv,
    unsigned short* __restrict__ Qo,
    unsigned short* __restrict__ Ko,
    unsigned short* __restrict__ Vt)
{
  __shared__ unsigned short As[128 * 32];
  __shared__ unsigned short Bs[128 * 32];
  const int id = blockIdx.x;
  const int lane = threadIdx.x & 63;
  const int wave = threadIdx.x >> 6;
  const int wm = wave >> 1, wn = wave & 1;
  const int cn = lane & 15, quad = lane >> 4;
  f32x4 acc[4][4];

  if (id < 512) {
    const int m0   = (id & 31) * 128;
    const int by   = id >> 5;
    const int wsel = by >> 3;
    const int n0   = (by & 7) * 128;
    gemm_tile(X, wsel ? Wk : Wq, m0, n0, As, Bs, acc);

    const float qscl = wsel ? 1.0f : 0.180336881f;   // 0.125 * log2(e)
    unsigned short* O = wsel ? Ko : Qo;
    #pragma unroll
    for (int i = 0; i < 4; ++i)
      #pragma unroll
      for (int j = 0; j < 4; ++j)
        #pragma unroll
        for (int r = 0; r < 4; ++r) {
          const int row = m0 + wm * 64 + i * 16 + quad * 4 + r;
          const int col = n0 + wn * 64 + j * 16 + cn;
          const int h = col >> 6, d = col & 63;
          O[(size_t)(h * LSEQ + row) * DH + d] = f2bf(acc[i][j][r] * qscl);
        }
  } else {
    const int vid = id - 512;
    const int m0 = (vid & 7) * 128;    // d-block (H*DH)
    const int n0 = (vid >> 3) * 128;   // token-block
    gemm_tile(Wv, X, m0, n0, As, Bs, acc);

    #pragma unroll
    for (int i = 0; i < 4; ++i)
      #pragma unroll
      for (int j = 0; j < 4; ++j)
        #pragma unroll
        for (int r = 0; r < 4; ++r) {
          const int row = m0 + wm * 64 + i * 16 + quad * 4 + r;   // d
          const int col = n0 + wn * 64 + j * 16 + cn;             // token
          Vt[(size_t)row * LSEQ + col] = f2bf(acc[i][j][r]);
        }
  }
}

// Output projection, 64x128 tiles: grid (64, 8), fp32 store
__global__ __launch_bounds__(256) void out_gemm(
    const unsigned short* __restrict__ X,
    const unsigned short* __restrict__ W,
    float* __restrict__ O)
{
  __shared__ unsigned short As2[64 * 32];
  __shared__ unsigned short Bs[128 * 32];
  const int m0 = blockIdx.x * 64;
  const int n0 = blockIdx.y * 128;
  const int tid  = threadIdx.x;
  const int lane = tid & 63;
  const int wave = tid >> 6;
  const int wm = wave >> 1, wn = wave & 1;
  const int fr = lane & 15, quad = lane >> 4;

  const f32x4 zero = {0.f, 0.f, 0.f, 0.f};
  f32x4 acc[2][4];
  #pragma unroll
  for (int i = 0; i < 2; ++i)
    #pragma unroll
    for (int j = 0; j < 4; ++j)
      acc[i][j] = zero;

  const unsigned short* xa  = X + (size_t)(m0 + (tid >> 2)) * DM + (tid & 3) * 8;
  const unsigned short* wb0 = W + (size_t)(n0 + (tid >> 2)) * DM + (tid & 3) * 8;
  const unsigned short* wb1 = W + (size_t)(n0 + ((tid + 256) >> 2)) * DM + (tid & 3) * 8;
  char* la  = (char*)As2 + tid * 16;
  char* lb0 = (char*)Bs + tid * 16;
  char* lb1 = (char*)Bs + (tid + 256) * 16;

  for (int kt = 0; kt < DM; kt += 32) {
    gl2lds16(xa + kt, la);
    gl2lds16(wb0 + kt, lb0);
    gl2lds16(wb1 + kt, lb1);
    __syncthreads();

    bf16x8 a[2], b[4];
    #pragma unroll
    for (int t = 0; t < 2; ++t)
      a[t] = *(const bf16x8*)(As2 + (wm * 32 + t * 16 + fr) * 32 + quad * 8);
    #pragma unroll
    for (int t = 0; t < 4; ++t)
      b[t] = *(const bf16x8*)(Bs + (wn * 64 + t * 16 + fr) * 32 + quad * 8);

    #pragma unroll
    for (int i = 0; i < 2; ++i)
      #pragma unroll
      for (int j = 0; j < 4; ++j)
        acc[i][j] = __builtin_amdgcn_mfma_f32_16x16x32_bf16(a[i], b[j], acc[i][j], 0, 0, 0);
    __syncthreads();
  }

  const int cn = lane & 15;
  #pragma unroll
  for (int i = 0; i < 2; ++i)
    #pragma unroll
    for (int j = 0; j < 4; ++j)
      #pragma unroll
      for (int r = 0; r < 4; ++r) {
        const int row = m0 + wm * 32 + i * 16 + quad * 4 + r;
        const int col = n0 + wn * 64 + j * 16 + cn;
        O[(size_t)row * DM + col] = acc[i][j][r];
      }
}

// Flash sliding-window attention, SPLIT-WINDOW (flash-decoding style).
// Block = 16 queries x 2 waves; each wave handles half the key tiles.
// Fixed-shift softmax => partials are exactly summable (no rescale):
//   out = (acc0 + acc1) / (l0 + l1).
// Grid 4096 blocks x 128 thr = 8192 waves = 32 waves/CU (hw max) to hide
// the per-iteration latency chain (R9-R11 showed attn is latency-bound).
// id bits: [2:0]=h-low, [10:3]=q-tile, [11]=h-high (stride-8 ids share K window).
#define PSTR 72
__global__ __launch_bounds__(128) void attn_fwd(
    const unsigned short* __restrict__ Q,
    const unsigned short* __restrict__ K,
    const unsigned short* __restrict__ Vt,
    unsigned short* __restrict__ Oa)
{
  __shared__ unsigned short Pl[2][16 * PSTR];
  __shared__ float Cmb[16][65];   // wave1 partial acc (pad: no 4-way banks)
  __shared__ float Lmb[16];       // wave1 partial denominators
  const int id   = blockIdx.x;
  const int h    = (id & 7) | ((id >> 11) << 3);
  const int qt   = (id >> 3) & 255;
  const int q0   = qt * 16;
  const int wave = threadIdx.x >> 6;
  const int lane = threadIdx.x & 63;
  const int n = lane & 15, quad = lane >> 4;
  unsigned short* pl = Pl[wave];

  const size_t qbase = ((size_t)(h * LSEQ + q0 + n)) * DH + quad * 8;
  const bf16x8 aq0 = *(const bf16x8*)(Q + qbase);   // Q pre-scaled by 0.125*log2e
  const bf16x8 aq1 = *(const bf16x8*)(Q + qbase + 32);

  // key-tile range for queries [q0, q0+15]: tiles [lo, hi], split across 2 waves
  const int lo = (q0 >= 255) ? ((q0 - 255) & ~63) : 0;
  const int hi = (q0 + 15) & ~63;
  const int ntile = ((hi - lo) >> 6) + 1;           // 1..5
  const int nw0 = (ntile + 1) >> 1;
  const int tb = (wave == 0) ? lo : lo + nw0 * 64;
  const int te = (wave == 0) ? lo + nw0 * 64 : hi + 64;

  const f32x4 zero = {0.f, 0.f, 0.f, 0.f};
  f32x4 acc[4] = {zero, zero, zero, zero};
  float li[4] = {0.f, 0.f, 0.f, 0.f};

  for (int jb = tb; jb < te; jb += 64) {
    // ---- QK scores for 4 x 16-key subtiles
    f32x4 s[4];
    #pragma unroll
    for (int u = 0; u < 4; ++u) {
      const size_t kbase = ((size_t)(h * LSEQ + jb + u * 16 + n)) * DH + quad * 8;
      const bf16x8 kb0 = *(const bf16x8*)(K + kbase);
      const bf16x8 kb1 = *(const bf16x8*)(K + kbase + 32);
      f32x4 c = zero;
      c = __builtin_amdgcn_mfma_f32_16x16x32_bf16(aq0, kb0, c, 0, 0, 0);
      c = __builtin_amdgcn_mfma_f32_16x16x32_bf16(aq1, kb1, c, 0, 0, 0);
      s[u] = c;
    }
    // ---- fixed-shift exp2 + per-lane partial denominator
    #pragma unroll
    for (int u = 0; u < 4; ++u)
      #pragma unroll
      for (int r = 0; r < 4; ++r) {
        const int qi = q0 + quad * 4 + r;
        const int kj = jb + u * 16 + n;
        const bool ok = (kj <= qi) && (kj + WIN > qi);
        const float e = __builtin_exp2f(ok ? s[u][r] - 32.0f : -1e30f);
        s[u][r] = e;
        li[r] += e;
      }
    // ---- P: C-layout regs -> per-wave LDS -> A-operand layout
    #pragma unroll
    for (int u = 0; u < 4; ++u)
      #pragma unroll
      for (int r = 0; r < 4; ++r)
        pl[(quad * 4 + r) * PSTR + u * 16 + n] = f2bf(s[u][r]);
    asm volatile("s_waitcnt lgkmcnt(0)" ::: "memory");   // wave-private LDS fence
    const bf16x8 pa0 = *(const bf16x8*)(pl + n * PSTR + quad * 8);
    const bf16x8 pa1 = *(const bf16x8*)(pl + n * PSTR + 32 + quad * 8);
    // ---- PV from V^T [H*DH][L]
    #pragma unroll
    for (int ct = 0; ct < 4; ++ct) {
      const size_t vb = ((size_t)(h * DH + ct * 16 + n)) * LSEQ + jb + quad * 8;
      const bf16x8 vb0 = *(const bf16x8*)(Vt + vb);
      const bf16x8 vb1 = *(const bf16x8*)(Vt + vb + 32);
      acc[ct] = __builtin_amdgcn_mfma_f32_16x16x32_bf16(pa0, vb0, acc[ct], 0, 0, 0);
      acc[ct] = __builtin_amdgcn_mfma_f32_16x16x32_bf16(pa1, vb1, acc[ct], 0, 0, 0);
    }
  }

  // ---- per-wave denominator reduction (16 lanes per quad-row)
  float lr[4];
  #pragma unroll
  for (int r = 0; r < 4; ++r) {
    float v = li[r];
    v += __shfl_xor(v, 1);
    v += __shfl_xor(v, 2);
    v += __shfl_xor(v, 4);
    v += __shfl_xor(v, 8);
    lr[r] = v;
  }

  // ---- combine: wave1 publishes partials; wave0 sums, normalizes, stores
  if (wave == 1) {
    #pragma unroll
    for (int ct = 0; ct < 4; ++ct)
      #pragma unroll
      for (int r = 0; r < 4; ++r)
        Cmb[quad * 4 + r][ct * 16 + n] = acc[ct][r];
    if (n == 0) {
      #pragma unroll
      for (int r = 0; r < 4; ++r)
        Lmb[quad * 4 + r] = lr[r];
    }
  }
  __syncthreads();
  if (wave == 0) {
    float rd[4];
    #pragma unroll
    for (int r = 0; r < 4; ++r)
      rd[r] = 1.0f / (lr[r] + Lmb[quad * 4 + r]);
    #pragma unroll
    for (int ct = 0; ct < 4; ++ct)
      #pragma unroll
      for (int r = 0; r < 4; ++r) {
        const int row = q0 + quad * 4 + r;
        const int col = h * DH + ct * 16 + n;
        const float o = (acc[ct][r] + Cmb[quad * 4 + r][ct * 16 + n]) * rd[r];
        Oa[(size_t)row * DM + col] = f2bf(o);
      }
  }
}

extern "C" void kernel_launch(void* const* d_in, const int* in_sizes, int n_in,
                              void* d_out, int out_size, void* d_ws, size_t ws_size,
                              hipStream_t stream) {
  const float* x  = (const float*)d_in[0];
  const float* Wq = (const float*)d_in[1];
  const float* Wk = (const float*)d_in[2];
  const float* Wv = (const float*)d_in[3];
  const float* Wo = (const float*)d_in[4];
  float* out = (float*)d_out;               // fp32 output (proven R6)

  unsigned short* xb  = (unsigned short*)d_ws;            // [L][DM]    8 MiB
  unsigned short* Wqb = xb  + (size_t)LSEQ * DM;          // 2 MiB each
  unsigned short* Wkb = Wqb + (size_t)DM * DM;
  unsigned short* Wvb = Wkb + (size_t)DM * DM;
  unsigned short* Wob = Wvb + (size_t)DM * DM;
  unsigned short* Q    = Wob + (size_t)DM * DM;           // [H][L][64] 8 MiB (pre-scaled)
  unsigned short* K    = Q   + (size_t)LSEQ * DM;
  unsigned short* Vt   = K   + (size_t)LSEQ * DM;         // [H*DH][L]
  unsigned short* Attn = Vt  + (size_t)LSEQ * DM;         // [L][DM]
  // total 48 MiB (ws >= 64 MiB, proven R4)

  cvt_all<<<dim3(4096), 256, 0, stream>>>(x, Wq, Wk, Wv, Wo, xb);
  proj_gemm<<<dim3(768), 256, 0, stream>>>(xb, Wqb, Wkb, Wvb, Q, K, Vt);
  attn_fwd<<<dim3(4096), 128, 0, stream>>>(Q, K, Vt, Attn);
  out_gemm<<<dim3(64, 8), 256, 0, stream>>>(Attn, Wob, out);
}

// Round 13
// 156.423 us; speedup vs baseline: 10.9192x; 1.1126x over previous
//
#include <hip/hip_runtime.h>

using bf16x8 = __attribute__((ext_vector_type(8))) short;
using u16x8  = __attribute__((ext_vector_type(8))) unsigned short;
using f32x4  = __attribute__((ext_vector_type(4))) float;

#define LSEQ   4096
#define NH     16
#define DH     64
#define WIN    256
#define DM     1024

// async global->LDS, 16B per lane; LDS dest is wave-uniform base + lane*16
__device__ __forceinline__ void gl2lds16(const void* g, void* l) {
  __builtin_amdgcn_global_load_lds(
      (const __attribute__((address_space(1))) unsigned int*)g,
      (__attribute__((address_space(3))) unsigned int*)l,
      16, 0, 0);
}

// fp32 -> bf16 RNE (finite inputs only)
__device__ __forceinline__ unsigned short f2bf(float f) {
  unsigned int u = __float_as_uint(f);
  u += 0x7fffu + ((u >> 16) & 1u);
  return (unsigned short)(u >> 16);
}

// ---- fp32 -> bf16, exact-size flat kernel over the contiguous ws image ----
__global__ __launch_bounds__(256) void cvt_all(
    const float* __restrict__ x,  const float* __restrict__ wq,
    const float* __restrict__ wk, const float* __restrict__ wv,
    const float* __restrict__ wo, unsigned short* __restrict__ dst)
{
  const size_t i = ((size_t)blockIdx.x * 256 + threadIdx.x) * 8;
  const size_t XN = (size_t)LSEQ * DM;          // 4M
  const float* src;
  size_t off;
  if (i < XN) { src = x; off = i; }
  else {
    const size_t j = i - XN;
    const int s = (int)(j >> 20);                // 1M elems per weight
    off = j & ((1u << 20) - 1);
    src = (s == 0) ? wq : (s == 1) ? wk : (s == 2) ? wv : wo;
  }
  const f32x4 f0 = *(const f32x4*)(src + off);
  const f32x4 f1 = *(const f32x4*)(src + off + 4);
  u16x8 o;
  o[0] = f2bf(f0[0]); o[1] = f2bf(f0[1]); o[2] = f2bf(f0[2]); o[3] = f2bf(f0[3]);
  o[4] = f2bf(f1[0]); o[5] = f2bf(f1[1]); o[6] = f2bf(f1[2]); o[7] = f2bf(f1[3]);
  *(u16x8*)(dst + i) = o;
}

// 128x128 NT GEMM tile (validated R2==R4): global_load_lds + 16x16x32 MFMA
__device__ __forceinline__ void gemm_tile(
    const unsigned short* __restrict__ X,
    const unsigned short* __restrict__ W,
    int m0, int n0,
    unsigned short* As, unsigned short* Bs,
    f32x4 (&acc)[4][4])
{
  const int tid  = threadIdx.x;
  const int lane = tid & 63;
  const int wave = tid >> 6;
  const int wm = wave >> 1, wn = wave & 1;
  const int fr = lane & 15, quad = lane >> 4;

  const f32x4 zero = {0.f, 0.f, 0.f, 0.f};
  #pragma unroll
  for (int i = 0; i < 4; ++i)
    #pragma unroll
    for (int j = 0; j < 4; ++j)
      acc[i][j] = zero;

  const int c0 = tid, c1 = tid + 256;
  const unsigned short* xa0 = X + (size_t)(m0 + (c0 >> 2)) * DM + (c0 & 3) * 8;
  const unsigned short* xa1 = X + (size_t)(m0 + (c1 >> 2)) * DM + (c1 & 3) * 8;
  const unsigned short* wb0 = W + (size_t)(n0 + (c0 >> 2)) * DM + (c0 & 3) * 8;
  const unsigned short* wb1 = W + (size_t)(n0 + (c1 >> 2)) * DM + (c1 & 3) * 8;
  char* la0 = (char*)As + c0 * 16;
  char* la1 = (char*)As + c1 * 16;
  char* lb0 = (char*)Bs + c0 * 16;
  char* lb1 = (char*)Bs + c1 * 16;

  for (int kt = 0; kt < DM; kt += 32) {
    gl2lds16(xa0 + kt, la0);
    gl2lds16(xa1 + kt, la1);
    gl2lds16(wb0 + kt, lb0);
    gl2lds16(wb1 + kt, lb1);
    __syncthreads();

    bf16x8 a[4], b[4];
    #pragma unroll
    for (int t = 0; t < 4; ++t)
      a[t] = *(const bf16x8*)(As + (wm * 64 + t * 16 + fr) * 32 + quad * 8);
    #pragma unroll
    for (int t = 0; t < 4; ++t)
      b[t] = *(const bf16x8*)(Bs + (wn * 64 + t * 16 + fr) * 32 + quad * 8);

    #pragma unroll
    for (int i = 0; i < 4; ++i)
      #pragma unroll
      for (int j = 0; j < 4; ++j)
        acc[i][j] = __builtin_amdgcn_mfma_f32_16x16x32_bf16(a[i], b[j], acc[i][j], 0, 0, 0);
    __syncthreads();
  }
}

// Merged projections, grid (768): id<512 Q/K; id>=512 V^T (operand swap)
__global__ __launch_bounds__(256) void proj_gemm(
    const unsigned short* __restrict__ X,
    const unsigned short* __restrict__ Wq,
    const unsigned short* __restrict__ Wk,
    const unsigned short* __restrict__ Wv,
    unsigned short* __restrict__ Qo,
    unsigned short* __restrict__ Ko,
    unsigned short* __restrict__ Vt)
{
  __shared__ unsigned short As[128 * 32];
  __shared__ unsigned short Bs[128 * 32];
  const int id = blockIdx.x;
  const int lane = threadIdx.x & 63;
  const int wave = threadIdx.x >> 6;
  const int wm = wave >> 1, wn = wave & 1;
  const int cn = lane & 15, quad = lane >> 4;
  f32x4 acc[4][4];

  if (id < 512) {
    const int m0   = (id & 31) * 128;
    const int by   = id >> 5;
    const int wsel = by >> 3;
    const int n0   = (by & 7) * 128;
    gemm_tile(X, wsel ? Wk : Wq, m0, n0, As, Bs, acc);

    const float qscl = wsel ? 1.0f : 0.180336881f;   // 0.125 * log2(e)
    unsigned short* O = wsel ? Ko : Qo;
    #pragma unroll
    for (int i = 0; i < 4; ++i)
      #pragma unroll
      for (int j = 0; j < 4; ++j)
        #pragma unroll
        for (int r = 0; r < 4; ++r) {
          const int row = m0 + wm * 64 + i * 16 + quad * 4 + r;
          const int col = n0 + wn * 64 + j * 16 + cn;
          const int h = col >> 6, d = col & 63;
          O[(size_t)(h * LSEQ + row) * DH + d] = f2bf(acc[i][j][r] * qscl);
        }
  } else {
    const int vid = id - 512;
    const int m0 = (vid & 7) * 128;    // d-block (H*DH)
    const int n0 = (vid >> 3) * 128;   // token-block
    gemm_tile(Wv, X, m0, n0, As, Bs, acc);

    #pragma unroll
    for (int i = 0; i < 4; ++i)
      #pragma unroll
      for (int j = 0; j < 4; ++j)
        #pragma unroll
        for (int r = 0; r < 4; ++r) {
          const int row = m0 + wm * 64 + i * 16 + quad * 4 + r;   // d
          const int col = n0 + wn * 64 + j * 16 + cn;             // token
          Vt[(size_t)row * LSEQ + col] = f2bf(acc[i][j][r]);
        }
  }
}

// Output projection, 64x128 tiles: grid (64, 8), fp32 store
__global__ __launch_bounds__(256) void out_gemm(
    const unsigned short* __restrict__ X,
    const unsigned short* __restrict__ W,
    float* __restrict__ O)
{
  __shared__ unsigned short As2[64 * 32];
  __shared__ unsigned short Bs[128 * 32];
  const int m0 = blockIdx.x * 64;
  const int n0 = blockIdx.y * 128;
  const int tid  = threadIdx.x;
  const int lane = tid & 63;
  const int wave = tid >> 6;
  const int wm = wave >> 1, wn = wave & 1;
  const int fr = lane & 15, quad = lane >> 4;

  const f32x4 zero = {0.f, 0.f, 0.f, 0.f};
  f32x4 acc[2][4];
  #pragma unroll
  for (int i = 0; i < 2; ++i)
    #pragma unroll
    for (int j = 0; j < 4; ++j)
      acc[i][j] = zero;

  const unsigned short* xa  = X + (size_t)(m0 + (tid >> 2)) * DM + (tid & 3) * 8;
  const unsigned short* wb0 = W + (size_t)(n0 + (tid >> 2)) * DM + (tid & 3) * 8;
  const unsigned short* wb1 = W + (size_t)(n0 + ((tid + 256) >> 2)) * DM + (tid & 3) * 8;
  char* la  = (char*)As2 + tid * 16;
  char* lb0 = (char*)Bs + tid * 16;
  char* lb1 = (char*)Bs + (tid + 256) * 16;

  for (int kt = 0; kt < DM; kt += 32) {
    gl2lds16(xa + kt, la);
    gl2lds16(wb0 + kt, lb0);
    gl2lds16(wb1 + kt, lb1);
    __syncthreads();

    bf16x8 a[2], b[4];
    #pragma unroll
    for (int t = 0; t < 2; ++t)
      a[t] = *(const bf16x8*)(As2 + (wm * 32 + t * 16 + fr) * 32 + quad * 8);
    #pragma unroll
    for (int t = 0; t < 4; ++t)
      b[t] = *(const bf16x8*)(Bs + (wn * 64 + t * 16 + fr) * 32 + quad * 8);

    #pragma unroll
    for (int i = 0; i < 2; ++i)
      #pragma unroll
      for (int j = 0; j < 4; ++j)
        acc[i][j] = __builtin_amdgcn_mfma_f32_16x16x32_bf16(a[i], b[j], acc[i][j], 0, 0, 0);
    __syncthreads();
  }

  const int cn = lane & 15;
  #pragma unroll
  for (int i = 0; i < 2; ++i)
    #pragma unroll
    for (int j = 0; j < 4; ++j)
      #pragma unroll
      for (int r = 0; r < 4; ++r) {
        const int row = m0 + wm * 32 + i * 16 + quad * 4 + r;
        const int col = n0 + wn * 64 + j * 16 + cn;
        O[(size_t)row * DM + col] = acc[i][j][r];
      }
}

// Flash sliding-window attention, block-cooperative LDS-staged K/V.
// R13: the one invariant across R9-R12 was per-wave GLOBAL K/V loads ->
// per-iter VMEM latency chain. Now: block = 1 head x 64 queries (4 waves),
// K/V tiles staged ONCE per block into padded LDS (register-staged
// ds_write_b128, double-buffered, next-tile global loads overlap compute,
// one barrier/iter). Waves consume K/V via short-latency LDS b128 reads.
// id bits as R11: stride-8 ids share the K window (XCD L2 locality).
#define PSTR 72
__global__ __launch_bounds__(256) void attn_fwd(
    const unsigned short* __restrict__ Q,
    const unsigned short* __restrict__ K,
    const unsigned short* __restrict__ Vt,
    unsigned short* __restrict__ Oa)
{
  __shared__ unsigned short Ks[2][64 * PSTR];   // 9216 B each
  __shared__ unsigned short Vs[2][64 * PSTR];
  __shared__ unsigned short Pl[4][16 * PSTR];   // per-wave P tiles
  const int id   = blockIdx.x;
  const int h    = (id & 7) | ((id >> 9) << 3);
  const int bq0  = ((id >> 3) & 63) * 64;
  const int tid  = threadIdx.x;
  const int wave = tid >> 6;
  const int lane = tid & 63;
  const int n = lane & 15, quad = lane >> 4;
  const int q0 = bq0 + wave * 16;
  unsigned short* pl = Pl[wave];

  const size_t qbase = ((size_t)(h * LSEQ + q0 + n)) * DH + quad * 8;
  const bf16x8 aq0 = *(const bf16x8*)(Q + qbase);   // Q pre-scaled by 0.125*log2e
  const bf16x8 aq1 = *(const bf16x8*)(Q + qbase + 32);

  const int lo = (bq0 >= WIN) ? (bq0 - WIN) : 0;    // first 64-key tile

  // staging map: 512 x 16B chunks per tile; thread t handles c = t, t+256.
  // chunk c -> row c>>3 (key or d), part c&7; LDS row stride PSTR (16B-aligned).
  const int c0 = tid, c1 = tid + 256;
  const size_t kg0 = ((size_t)(h * LSEQ + (c0 >> 3))) * DH + (c0 & 7) * 8;
  const size_t kg1 = ((size_t)(h * LSEQ + (c1 >> 3))) * DH + (c1 & 7) * 8;
  const size_t vg0 = ((size_t)(h * DH + (c0 >> 3))) * LSEQ + (c0 & 7) * 8;
  const size_t vg1 = ((size_t)(h * DH + (c1 >> 3))) * LSEQ + (c1 & 7) * 8;
  const int ld0 = (c0 >> 3) * PSTR + (c0 & 7) * 8;
  const int ld1 = (c1 >> 3) * PSTR + (c1 & 7) * 8;

  // prologue: stage tile 0 into buffer 0
  {
    const bf16x8 ka = *(const bf16x8*)(K  + kg0 + (size_t)lo * DH);
    const bf16x8 kc = *(const bf16x8*)(K  + kg1 + (size_t)lo * DH);
    const bf16x8 va = *(const bf16x8*)(Vt + vg0 + lo);
    const bf16x8 vc = *(const bf16x8*)(Vt + vg1 + lo);
    *(bf16x8*)(Ks[0] + ld0) = ka;
    *(bf16x8*)(Ks[0] + ld1) = kc;
    *(bf16x8*)(Vs[0] + ld0) = va;
    *(bf16x8*)(Vs[0] + ld1) = vc;
  }
  __syncthreads();

  const f32x4 zero = {0.f, 0.f, 0.f, 0.f};
  f32x4 acc[4] = {zero, zero, zero, zero};
  float li[4] = {0.f, 0.f, 0.f, 0.f};

  int t = 0;
  for (int jb = lo; jb < bq0 + 64; jb += 64, ++t) {
    const int buf = t & 1;
    const bool more = (jb + 64 < bq0 + 64);
    // ---- issue next tile's global loads (overlap entire compute phase)
    bf16x8 nk0, nk1, nv0, nv1;
    if (more) {
      const int jn = jb + 64;
      nk0 = *(const bf16x8*)(K  + kg0 + (size_t)jn * DH);
      nk1 = *(const bf16x8*)(K  + kg1 + (size_t)jn * DH);
      nv0 = *(const bf16x8*)(Vt + vg0 + jn);
      nv1 = *(const bf16x8*)(Vt + vg1 + jn);
    }
    const unsigned short* ks = Ks[buf];
    const unsigned short* vs = Vs[buf];
    // ---- QK scores from LDS K
    f32x4 s[4];
    #pragma unroll
    for (int u = 0; u < 4; ++u) {
      const bf16x8 kb0 = *(const bf16x8*)(ks + (u * 16 + n) * PSTR + quad * 8);
      const bf16x8 kb1 = *(const bf16x8*)(ks + (u * 16 + n) * PSTR + 32 + quad * 8);
      f32x4 c = zero;
      c = __builtin_amdgcn_mfma_f32_16x16x32_bf16(aq0, kb0, c, 0, 0, 0);
      c = __builtin_amdgcn_mfma_f32_16x16x32_bf16(aq1, kb1, c, 0, 0, 0);
      s[u] = c;
    }
    // ---- fixed-shift exp2 + per-lane partial denominator
    #pragma unroll
    for (int u = 0; u < 4; ++u)
      #pragma unroll
      for (int r = 0; r < 4; ++r) {
        const int qi = q0 + quad * 4 + r;
        const int kj = jb + u * 16 + n;
        const bool ok = (kj <= qi) && (kj + WIN > qi);
        const float e = __builtin_exp2f(ok ? s[u][r] - 32.0f : -1e30f);
        s[u][r] = e;
        li[r] += e;
      }
    // ---- P: C-layout regs -> per-wave LDS -> A-operand layout
    #pragma unroll
    for (int u = 0; u < 4; ++u)
      #pragma unroll
      for (int r = 0; r < 4; ++r)
        pl[(quad * 4 + r) * PSTR + u * 16 + n] = f2bf(s[u][r]);
    asm volatile("s_waitcnt lgkmcnt(0)" ::: "memory");   // wave-private LDS fence
    const bf16x8 pa0 = *(const bf16x8*)(pl + n * PSTR + quad * 8);
    const bf16x8 pa1 = *(const bf16x8*)(pl + n * PSTR + 32 + quad * 8);
    // ---- PV from LDS V
    #pragma unroll
    for (int ct = 0; ct < 4; ++ct) {
      const bf16x8 vb0 = *(const bf16x8*)(vs + (ct * 16 + n) * PSTR + quad * 8);
      const bf16x8 vb1 = *(const bf16x8*)(vs + (ct * 16 + n) * PSTR + 32 + quad * 8);
      acc[ct] = __builtin_amdgcn_mfma_f32_16x16x32_bf16(pa0, vb0, acc[ct], 0, 0, 0);
      acc[ct] = __builtin_amdgcn_mfma_f32_16x16x32_bf16(pa1, vb1, acc[ct], 0, 0, 0);
    }
    // ---- write next tile into the other buffer, then one barrier
    if (more) {
      *(bf16x8*)(Ks[buf ^ 1] + ld0) = nk0;
      *(bf16x8*)(Ks[buf ^ 1] + ld1) = nk1;
      *(bf16x8*)(Vs[buf ^ 1] + ld0) = nv0;
      *(bf16x8*)(Vs[buf ^ 1] + ld1) = nv1;
    }
    __syncthreads();
  }

  // ---- single cross-lane denominator reduction
  float rd[4];
  #pragma unroll
  for (int r = 0; r < 4; ++r) {
    float v = li[r];
    v += __shfl_xor(v, 1);
    v += __shfl_xor(v, 2);
    v += __shfl_xor(v, 4);
    v += __shfl_xor(v, 8);
    rd[r] = 1.0f / v;
  }
  #pragma unroll
  for (int ct = 0; ct < 4; ++ct)
    #pragma unroll
    for (int r = 0; r < 4; ++r) {
      const int row = q0 + quad * 4 + r;
      const int col = h * DH + ct * 16 + n;
      Oa[(size_t)row * DM + col] = f2bf(acc[ct][r] * rd[r]);
    }
}

extern "C" void kernel_launch(void* const* d_in, const int* in_sizes, int n_in,
                              void* d_out, int out_size, void* d_ws, size_t ws_size,
                              hipStream_t stream) {
  const float* x  = (const float*)d_in[0];
  const float* Wq = (const float*)d_in[1];
  const float* Wk = (const float*)d_in[2];
  const float* Wv = (const float*)d_in[3];
  const float* Wo = (const float*)d_in[4];
  float* out = (float*)d_out;               // fp32 output (proven R6)

  unsigned short* xb  = (unsigned short*)d_ws;            // [L][DM]    8 MiB
  unsigned short* Wqb = xb  + (size_t)LSEQ * DM;          // 2 MiB each
  unsigned short* Wkb = Wqb + (size_t)DM * DM;
  unsigned short* Wvb = Wkb + (size_t)DM * DM;
  unsigned short* Wob = Wvb + (size_t)DM * DM;
  unsigned short* Q    = Wob + (size_t)DM * DM;           // [H][L][64] 8 MiB (pre-scaled)
  unsigned short* K    = Q   + (size_t)LSEQ * DM;
  unsigned short* Vt   = K   + (size_t)LSEQ * DM;         // [H*DH][L]
  unsigned short* Attn = Vt  + (size_t)LSEQ * DM;         // [L][DM]
  // total 48 MiB (ws >= 64 MiB, proven R4)

  cvt_all<<<dim3(4096), 256, 0, stream>>>(x, Wq, Wk, Wv, Wo, xb);
  proj_gemm<<<dim3(768), 256, 0, stream>>>(xb, Wqb, Wkb, Wvb, Q, K, Vt);
  attn_fwd<<<dim3(1024), 256, 0, stream>>>(Q, K, Vt, Attn);
  out_gemm<<<dim3(64, 8), 256, 0, stream>>>(Attn, Wob, out);
}